// Round 1
// baseline (2660.859 us; speedup 1.0000x reference)
//
#include <hip/hip_runtime.h>
#include <hip/hip_bf16.h>

// Sizes
#define NB 128
#define CIN 30
#define HW 15
#define OC 256
#define H1 13   // conv1 out
#define H2 11   // conv2 out
#define NCAPS 3872
#define IND 8
#define OUTD 16
#define CLS 16
#define D1 328
#define D2 192
#define OUTPIX 6750   // 30*15*15
#define NSPLIT 64
#define NPB 61        // ceil(3872/64)

// ---------------- conv1: x[128,30,15,15] -> h[128,256,13,13] ----------------
__global__ __launch_bounds__(256) void conv1_k(const float* __restrict__ x,
    const float* __restrict__ w, const float* __restrict__ bias, float* __restrict__ h) {
  int tid = blockIdx.x * blockDim.x + threadIdx.x;
  const int total = NB * OC * H1;
  if (tid >= total) return;
  int oy = tid % H1;
  int q = tid / H1;          // b*256+oc
  int oc = q & 255;
  int b = q >> 8;
  float acc[H1];
  float bs = bias[oc];
#pragma unroll
  for (int i = 0; i < H1; i++) acc[i] = bs;
  const float* xb = x + b * CIN * HW * HW;
  const float* wb = w + oc * CIN * 9;
  for (int ic = 0; ic < CIN; ic++) {
    const float* xc = xb + ic * (HW * HW) + oy * HW;
    float wv[9];
#pragma unroll
    for (int t = 0; t < 9; t++) wv[t] = wb[ic * 9 + t];
#pragma unroll
    for (int ky = 0; ky < 3; ky++) {
      float xr[HW];
#pragma unroll
      for (int xx = 0; xx < HW; xx++) xr[xx] = xc[ky * HW + xx];
#pragma unroll
      for (int kx = 0; kx < 3; kx++) {
        float wvv = wv[ky * 3 + kx];
#pragma unroll
        for (int ox = 0; ox < H1; ox++) acc[ox] += xr[ox + kx] * wvv;
      }
    }
  }
  float* hp = h + q * (H1 * H1) + oy * H1;
#pragma unroll
  for (int ox = 0; ox < H1; ox++) hp[ox] = acc[ox];
}

// ---------------- BN stats: per-channel mean / invstd over B*13*13 ----------
__global__ __launch_bounds__(256) void bn_stats_k(const float* __restrict__ h,
    float* __restrict__ mean, float* __restrict__ istd) {
  int c = blockIdx.x;
  int t = threadIdx.x;
  float s = 0.f, s2 = 0.f;
  const int per = H1 * H1;               // 169
  for (int i = t; i < NB * per; i += 256) {
    int b = i / per, pos = i - b * per;
    float v = h[(b * OC + c) * per + pos];
    s += v; s2 += v * v;
  }
  __shared__ float ls[256], ls2[256];
  ls[t] = s; ls2[t] = s2; __syncthreads();
  for (int off = 128; off > 0; off >>= 1) {
    if (t < off) { ls[t] += ls[t + off]; ls2[t] += ls2[t + off]; }
    __syncthreads();
  }
  if (t == 0) {
    const float inv_n = 1.0f / (NB * per);
    float m = ls[0] * inv_n;
    float v = ls2[0] * inv_n - m * m;
    mean[c] = m;
    istd[c] = rsqrtf(v + 1e-5f);
  }
}

// ---------------- BN apply + relu (in place on h) ---------------------------
__global__ __launch_bounds__(256) void bn_apply_k(float* __restrict__ h,
    const float* __restrict__ mean, const float* __restrict__ istd,
    const float* __restrict__ gamma, const float* __restrict__ beta) {
  int bc = blockIdx.x;           // b*256+c
  int c = bc & 255;
  int t = threadIdx.x;
  if (t >= H1 * H1) return;
  float v = h[bc * (H1 * H1) + t];
  v = (v - mean[c]) * istd[c] * gamma[c] + beta[c];
  h[bc * (H1 * H1) + t] = fmaxf(v, 0.0f);
}

// ---------------- conv2: h[128,256,13,13] -> p[128,256,11,11] ---------------
__global__ __launch_bounds__(256) void conv2_k(const float* __restrict__ h,
    const float* __restrict__ w, const float* __restrict__ bias, float* __restrict__ p) {
  int tid = blockIdx.x * blockDim.x + threadIdx.x;
  const int total = NB * OC * H2;
  if (tid >= total) return;
  int oy = tid % H2;
  int q = tid / H2;          // b*256+oc
  int oc = q & 255;
  int b = q >> 8;
  float acc[H2];
  float bs = bias[oc];
#pragma unroll
  for (int i = 0; i < H2; i++) acc[i] = bs;
  const float* hb = h + b * OC * (H1 * H1);
  const float* wb = w + oc * OC * 9;
  for (int ic = 0; ic < OC; ic++) {
    const float* hc = hb + ic * (H1 * H1) + oy * H1;
    float wv[9];
#pragma unroll
    for (int t = 0; t < 9; t++) wv[t] = wb[ic * 9 + t];
#pragma unroll
    for (int ky = 0; ky < 3; ky++) {
      float xr[H1];
#pragma unroll
      for (int xx = 0; xx < H1; xx++) xr[xx] = hc[ky * H1 + xx];
#pragma unroll
      for (int kx = 0; kx < 3; kx++) {
        float wvv = wv[ky * 3 + kx];
#pragma unroll
        for (int ox = 0; ox < H2; ox++) acc[ox] += xr[ox + kx] * wvv;
      }
    }
  }
  float* pp = p + q * (H2 * H2) + oy * H2;
#pragma unroll
  for (int ox = 0; ox < H2; ox++) pp[ox] = acc[ox];
}

// ---------------- squash primary caps: p flat groups of 8 -------------------
__global__ __launch_bounds__(256) void squash_caps_k(const float* __restrict__ p,
    float* __restrict__ caps) {
  int tid = blockIdx.x * blockDim.x + threadIdx.x;
  const int total = NB * NCAPS;
  if (tid >= total) return;
  const float4* src = (const float4*)(p + (size_t)tid * 8);
  float4 a = src[0], b4 = src[1];
  float n2 = a.x * a.x + a.y * a.y + a.z * a.z + a.w * a.w +
             b4.x * b4.x + b4.y * b4.y + b4.z * b4.z + b4.w * b4.w;
  float nrm = sqrtf(n2);
  float scale = n2 / (1.0f + n2) / (nrm + 1e-8f);
  a.x *= scale; a.y *= scale; a.z *= scale; a.w *= scale;
  b4.x *= scale; b4.y *= scale; b4.z *= scale; b4.w *= scale;
  float4* dst = (float4*)(caps + (size_t)tid * 8);
  dst[0] = a; dst[1] = b4;
}

// ---------------- routing pass: s_part = sum_n softmax_o(osum.xh) * xh ------
// xh recomputed from caps_w & caps. lane=(b_sub,o); softmax via 16-lane butterfly.
__global__ __launch_bounds__(512) void route_k(const float* __restrict__ caps,
    const float* __restrict__ cw, const float* __restrict__ osum,
    float* __restrict__ spart) {
  int split = blockIdx.x;      // 0..63
  int btile = blockIdx.y;      // 0..3
  int t = threadIdx.x;         // 0..511
  int o = t & 15;
  int bl = t >> 4;             // 0..31
  int b = btile * 32 + bl;
  float os[16];
  const float* op = osum + (b * 16 + o) * 16;
#pragma unroll
  for (int i = 0; i < 16; i++) os[i] = op[i];
  float sacc[16];
#pragma unroll
  for (int i = 0; i < 16; i++) sacc[i] = 0.f;
  int nbeg = split * NPB;
  int nend = nbeg + NPB; if (nend > NCAPS) nend = NCAPS;
  for (int n = nbeg; n < nend; n++) {
    const float4* cp = (const float4*)(caps + ((size_t)b * NCAPS + n) * 8);
    float4 c0 = cp[0], c1 = cp[1];
    float xh[16];
    const float* wp = cw + (((size_t)o * NCAPS + n) * 16) * 8;
#pragma unroll
    for (int i = 0; i < 16; i++) {
      const float4* w4 = (const float4*)(wp + i * 8);
      float4 a = w4[0], bb = w4[1];
      xh[i] = a.x * c0.x + a.y * c0.y + a.z * c0.z + a.w * c0.w +
              bb.x * c1.x + bb.y * c1.y + bb.z * c1.z + bb.w * c1.w;
    }
    float blog = 0.f;
#pragma unroll
    for (int i = 0; i < 16; i++) blog += os[i] * xh[i];
    // softmax over o (aligned 16-lane group butterfly)
    float m = blog;
#pragma unroll
    for (int d = 1; d < 16; d <<= 1) m = fmaxf(m, __shfl_xor(m, d));
    float e = __expf(blog - m);
    float ssum = e;
#pragma unroll
    for (int d = 1; d < 16; d <<= 1) ssum += __shfl_xor(ssum, d);
    float cc = e / ssum;
#pragma unroll
    for (int i = 0; i < 16; i++) sacc[i] += cc * xh[i];
  }
  float* sp = spart + (((size_t)split * NB + b) * 16 + o) * 16;
#pragma unroll
  for (int i = 0; i < 16; i++) sp[i] = sacc[i];
}

// ---------------- combine partials + squash + osum update -------------------
__global__ __launch_bounds__(256) void combine_squash_k(const float* __restrict__ spart,
    float* __restrict__ osum, float* __restrict__ outbuf, const float* __restrict__ y,
    float* __restrict__ masked, float* __restrict__ length_out, int last) {
  int tid = blockIdx.x * blockDim.x + threadIdx.x;   // 32768 = 128*16*16
  int i = tid & 15;
  int o = (tid >> 4) & 15;
  int b = tid >> 8;
  float s = 0.f;
  for (int k = 0; k < NSPLIT; k++) s += spart[k * 32768 + tid];
  float n2 = s * s;
#pragma unroll
  for (int d = 1; d < 16; d <<= 1) n2 += __shfl_xor(n2, d);
  float nrm = sqrtf(n2);
  float scale = n2 / (1.f + n2) / (nrm + 1e-8f);
  float ov = scale * s;
  outbuf[tid] = ov;
  osum[tid] += ov;
  if (last) {
    masked[tid] = ov * y[b * 16 + o];
    if (i == 0) length_out[b * 16 + o] = scale * nrm;
  }
}

// ---------------- decoder -----------------------------------------------------
__global__ __launch_bounds__(256) void dec1_k(const float* __restrict__ masked,
    const float* __restrict__ w1, const float* __restrict__ b1, float* __restrict__ r1) {
  int tid = blockIdx.x * blockDim.x + threadIdx.x;
  if (tid >= NB * D1) return;
  int j = tid % D1;
  int b = tid / D1;
  const float* mp = masked + b * 256;
  float acc = b1[j];
  for (int k = 0; k < 256; k++) acc += mp[k] * w1[k * D1 + j];
  r1[tid] = 1.f / (1.f + __expf(-acc));
}

__global__ __launch_bounds__(256) void dec2_k(const float* __restrict__ r1,
    const float* __restrict__ w2, const float* __restrict__ b2, float* __restrict__ r2) {
  int tid = blockIdx.x * blockDim.x + threadIdx.x;
  if (tid >= NB * D2) return;
  int j = tid % D2;
  int b = tid / D2;
  const float* rp = r1 + b * D1;
  float acc = b2[j];
  for (int k = 0; k < D1; k++) acc += rp[k] * w2[k * D2 + j];
  r2[tid] = 1.f / (1.f + __expf(-acc));
}

// block: 64 m-cols x 4 b-groups(16 b each); r2 chunk for 64 b staged in LDS [k][b]
__global__ __launch_bounds__(256) void dec3_k(const float* __restrict__ r2,
    const float* __restrict__ w3, const float* __restrict__ b3, float* __restrict__ recon) {
  __shared__ float r2s[D2 * 64];
  int mt = blockIdx.x, bh = blockIdx.y;
  int t = threadIdx.x;
  int b0 = bh * 64;
  for (int idx = t; idx < D2 * 64; idx += 256) {
    int bb = idx / D2, k = idx - bb * D2;
    r2s[k * 64 + bb] = r2[(b0 + bb) * D2 + k];
  }
  __syncthreads();
  int moff = t & 63, bg = t >> 6;      // whole wave shares bg -> LDS broadcast reads
  int m = mt * 64 + moff;
  if (m >= OUTPIX) return;
  float acc[16];
#pragma unroll
  for (int q = 0; q < 16; q++) acc[q] = 0.f;
  for (int k = 0; k < D2; k++) {
    float wv = w3[k * OUTPIX + m];
    const float4* r4 = (const float4*)&r2s[k * 64 + bg * 16];
#pragma unroll
    for (int v = 0; v < 4; v++) {
      float4 rv = r4[v];
      acc[v * 4 + 0] += wv * rv.x;
      acc[v * 4 + 1] += wv * rv.y;
      acc[v * 4 + 2] += wv * rv.z;
      acc[v * 4 + 3] += wv * rv.w;
    }
  }
  float bias = b3[m];
#pragma unroll
  for (int q = 0; q < 16; q++) {
    int b = b0 + bg * 16 + q;
    recon[(size_t)b * OUTPIX + m] = acc[q] + bias;
  }
}

extern "C" void kernel_launch(void* const* d_in, const int* in_sizes, int n_in,
                              void* d_out, int out_size, void* d_ws, size_t ws_size,
                              hipStream_t stream) {
  const float* x      = (const float*)d_in[0];
  const float* y      = (const float*)d_in[1];
  const float* conv1w = (const float*)d_in[2];
  const float* conv1b = (const float*)d_in[3];
  const float* gamma  = (const float*)d_in[4];
  const float* beta   = (const float*)d_in[5];
  const float* conv2w = (const float*)d_in[6];
  const float* conv2b = (const float*)d_in[7];
  const float* capsw  = (const float*)d_in[8];
  const float* w1     = (const float*)d_in[9];
  const float* b1     = (const float*)d_in[10];
  const float* w2     = (const float*)d_in[11];
  const float* b2     = (const float*)d_in[12];
  const float* w3     = (const float*)d_in[13];
  const float* b3     = (const float*)d_in[14];

  float* ws = (float*)d_ws;
  float* h      = ws;                    // 128*256*169   = 5537792
  float* p      = h + 5537792;           // 128*256*121   = 3964928
  float* caps   = p + 3964928;           // 128*3872*8    = 3964928
  float* mean   = caps + 3964928;        // 256
  float* istd   = mean + 256;            // 256
  float* osum   = istd + 256;            // 32768
  float* spart  = osum + 32768;          // 64*128*256    = 2097152
  float* outb   = spart + 2097152;       // 32768
  float* masked = outb + 32768;          // 32768
  float* r1     = masked + 32768;        // 128*328 = 41984
  float* r2     = r1 + 41984;            // 128*192 = 24576

  float* length_out = (float*)d_out;           // 2048
  float* recon      = (float*)d_out + 2048;    // 864000

  // conv stem
  {
    int total = NB * OC * H1;
    conv1_k<<<(total + 255) / 256, 256, 0, stream>>>(x, conv1w, conv1b, h);
  }
  bn_stats_k<<<OC, 256, 0, stream>>>(h, mean, istd);
  bn_apply_k<<<NB * OC, 256, 0, stream>>>(h, mean, istd, gamma, beta);
  {
    int total = NB * OC * H2;
    conv2_k<<<(total + 255) / 256, 256, 0, stream>>>(h, conv2w, conv2b, p);
  }
  {
    int total = NB * NCAPS;
    squash_caps_k<<<(total + 255) / 256, 256, 0, stream>>>(p, caps);
  }

  // dynamic routing (3 iterations), osum = sum of previous outs
  hipMemsetAsync(osum, 0, 32768 * sizeof(float), stream);
  for (int it = 0; it < 3; ++it) {
    route_k<<<dim3(NSPLIT, 4), 512, 0, stream>>>(caps, capsw, osum, spart);
    combine_squash_k<<<128, 256, 0, stream>>>(spart, osum, outb, y, masked,
                                              length_out, it == 2 ? 1 : 0);
  }

  // decoder
  dec1_k<<<(NB * D1 + 255) / 256, 256, 0, stream>>>(masked, w1, b1, r1);
  dec2_k<<<(NB * D2 + 255) / 256, 256, 0, stream>>>(r1, w2, b2, r2);
  dec3_k<<<dim3((OUTPIX + 63) / 64, 2), 256, 0, stream>>>(r2, w3, b3, recon);
}

// Round 2
// 1694.954 us; speedup vs baseline: 1.5699x; 1.5699x over previous
//
#include <hip/hip_runtime.h>
#include <hip/hip_bf16.h>

// Sizes
#define NB 128
#define CIN 30
#define HW 15
#define OC 256
#define H1 13   // conv1 out
#define H2 11   // conv2 out
#define NCAPS 3872
#define IND 8
#define OUTD 16
#define CLS 16
#define D1 328
#define D2 192
#define OUTPIX 6750   // 30*15*15
#define NSPLIT 64
#define NPB 61        // ceil(3872/64)

typedef __attribute__((ext_vector_type(8))) short short8_t;
typedef __attribute__((ext_vector_type(4))) float f32x4;

__device__ inline unsigned bf16rne(float f) {
  unsigned u = __builtin_bit_cast(unsigned, f);
  return (u + 0x7FFF + ((u >> 16) & 1)) >> 16;
}

// ---------------- conv1: x[128,30,15,15] -> h[128,256,13,13] ----------------
__global__ __launch_bounds__(256) void conv1_k(const float* __restrict__ x,
    const float* __restrict__ w, const float* __restrict__ bias, float* __restrict__ h) {
  int tid = blockIdx.x * blockDim.x + threadIdx.x;
  const int total = NB * OC * H1;
  if (tid >= total) return;
  int oy = tid % H1;
  int q = tid / H1;          // b*256+oc
  int oc = q & 255;
  int b = q >> 8;
  float acc[H1];
  float bs = bias[oc];
#pragma unroll
  for (int i = 0; i < H1; i++) acc[i] = bs;
  const float* xb = x + b * CIN * HW * HW;
  const float* wb = w + oc * CIN * 9;
  for (int ic = 0; ic < CIN; ic++) {
    const float* xc = xb + ic * (HW * HW) + oy * HW;
    float wv[9];
#pragma unroll
    for (int t = 0; t < 9; t++) wv[t] = wb[ic * 9 + t];
#pragma unroll
    for (int ky = 0; ky < 3; ky++) {
      float xr[HW];
#pragma unroll
      for (int xx = 0; xx < HW; xx++) xr[xx] = xc[ky * HW + xx];
#pragma unroll
      for (int kx = 0; kx < 3; kx++) {
        float wvv = wv[ky * 3 + kx];
#pragma unroll
        for (int ox = 0; ox < H1; ox++) acc[ox] += xr[ox + kx] * wvv;
      }
    }
  }
  float* hp = h + q * (H1 * H1) + oy * H1;
#pragma unroll
  for (int ox = 0; ox < H1; ox++) hp[ox] = acc[ox];
}

// ---------------- BN stats: per-channel mean / invstd over B*13*13 ----------
__global__ __launch_bounds__(256) void bn_stats_k(const float* __restrict__ h,
    float* __restrict__ mean, float* __restrict__ istd) {
  int c = blockIdx.x;
  int t = threadIdx.x;
  float s = 0.f, s2 = 0.f;
  const int per = H1 * H1;               // 169
  for (int i = t; i < NB * per; i += 256) {
    int b = i / per, pos = i - b * per;
    float v = h[(b * OC + c) * per + pos];
    s += v; s2 += v * v;
  }
  __shared__ float ls[256], ls2[256];
  ls[t] = s; ls2[t] = s2; __syncthreads();
  for (int off = 128; off > 0; off >>= 1) {
    if (t < off) { ls[t] += ls[t + off]; ls2[t] += ls2[t + off]; }
    __syncthreads();
  }
  if (t == 0) {
    const float inv_n = 1.0f / (NB * per);
    float m = ls[0] * inv_n;
    float v = ls2[0] * inv_n - m * m;
    mean[c] = m;
    istd[c] = rsqrtf(v + 1e-5f);
  }
}

// ---------------- BN apply + relu (in place on h) ---------------------------
__global__ __launch_bounds__(256) void bn_apply_k(float* __restrict__ h,
    const float* __restrict__ mean, const float* __restrict__ istd,
    const float* __restrict__ gamma, const float* __restrict__ beta) {
  int bc = blockIdx.x;           // b*256+c
  int c = bc & 255;
  int t = threadIdx.x;
  if (t >= H1 * H1) return;
  float v = h[bc * (H1 * H1) + t];
  v = (v - mean[c]) * istd[c] * gamma[c] + beta[c];
  h[bc * (H1 * H1) + t] = fmaxf(v, 0.0f);
}

// ---------------- pack conv2 weights to MFMA layout -------------------------
// w[oc][ic][3][3] f32 -> wpk[(ky*3+kx)][icchunk(32)][oc(256)][8ic] bf16
__global__ __launch_bounds__(256) void pack_w2_k(const float* __restrict__ w,
    unsigned short* __restrict__ wpk) {
  int tid = blockIdx.x * blockDim.x + threadIdx.x;    // 589824
  int e = tid & 7;
  int oc = (tid >> 3) & 255;
  int icchunk = (tid >> 11) & 31;
  int kykx = tid >> 16;
  int ic = icchunk * 8 + e;
  wpk[tid] = (unsigned short)bf16rne(w[((size_t)oc * 256 + ic) * 9 + kykx]);
}

// ---------------- conv2 via bf16 MFMA implicit GEMM -------------------------
// block = (image b, oc-half). LDS: whole image [169 pix][272 ic-pad] bf16.
// 8 waves: (wm 0..1) x (wn 0..3); each wave 4 mfrag x 2 nfrag of 16x16x32.
__global__ __launch_bounds__(512, 1) void conv2_mfma_k(
    const float* __restrict__ h, const unsigned short* __restrict__ wpk,
    const float* __restrict__ bias, float* __restrict__ p) {
  __shared__ char smem[169 * 544];       // 91936 B; reused for C transpose
  unsigned* hs32 = (unsigned*)smem;      // [pix][136] u32  (272 bf16, 16 pad)
  int bid = blockIdx.x;                  // 0..255
  int b = bid >> 1;
  int nh = bid & 1;                      // oc half
  int t = threadIdx.x;
  int l = t & 63, wid = t >> 6;

  // ---- stage image to LDS (transpose [ic][pix] -> [pix][ic], fp32->bf16)
  {
    const float* hb = h + (size_t)b * 256 * 169;
    for (int icp = wid; icp < 128; icp += 8) {
      const float* s0 = hb + (size_t)icp * 2 * 169;
#pragma unroll
      for (int pb = 0; pb < 3; pb++) {
        int pix = pb * 64 + l;
        if (pix < 169) {
          unsigned u0 = bf16rne(s0[pix]);
          unsigned u1 = bf16rne(s0[169 + pix]);
          hs32[pix * 136 + icp] = u0 | (u1 << 16);
        }
      }
    }
  }
  __syncthreads();

  int wm = wid & 1;        // m offset wm*64
  int wn = wid >> 1;       // n offset wn*32
  int row = l & 15, kc = l >> 4;
  int ocb = nh * 128 + wn * 32;          // + nf*16 + row -> oc

  int abase[4];
#pragma unroll
  for (int mf = 0; mf < 4; mf++) {
    int m = wm * 64 + mf * 16 + row;
    int p0 = (m < 121) ? ((m / 11) * 13 + (m % 11)) : 0;
    abase[mf] = p0 * 544 + kc * 16;
  }

  f32x4 acc[4][2];
#pragma unroll
  for (int mf = 0; mf < 4; mf++)
#pragma unroll
    for (int nf = 0; nf < 2; nf++)
      acc[mf][nf] = (f32x4){0.f, 0.f, 0.f, 0.f};

  // per-lane constant part of wpk element index
  const size_t lanebase = ((size_t)kc * 256 + ocb + row) * 8;
  const char* lds_base = (const char*)smem;

  for (int ky = 0; ky < 3; ky++) {
    for (int kx = 0; kx < 3; kx++) {
      int r = ky * 3 + kx;
      int koff = (ky * 13 + kx) * 544;
#pragma unroll
      for (int ks = 0; ks < 8; ks++) {
        short8_t bfr[2];
#pragma unroll
        for (int nf = 0; nf < 2; nf++) {
          size_t idx = lanebase + (size_t)(r * 32 + ks * 4) * 2048 + nf * 128;
          bfr[nf] = *(const short8_t*)(wpk + idx);
        }
        short8_t af[4];
#pragma unroll
        for (int mf = 0; mf < 4; mf++)
          af[mf] = *(const short8_t*)(lds_base + (abase[mf] + koff + ks * 64));
#pragma unroll
        for (int mf = 0; mf < 4; mf++)
#pragma unroll
          for (int nf = 0; nf < 2; nf++)
            acc[mf][nf] = __builtin_amdgcn_mfma_f32_16x16x32_bf16(
                af[mf], bfr[nf], acc[mf][nf], 0, 0, 0);
      }
    }
  }

  // ---- transpose C through LDS, store coalesced
  __syncthreads();                       // done reading A
  float* cl = (float*)smem;              // [ocl 0..127][132 m-pad]
#pragma unroll
  for (int nf = 0; nf < 2; nf++) {
    int ocl = wn * 32 + nf * 16 + row;
#pragma unroll
    for (int mf = 0; mf < 4; mf++) {
      int m0 = wm * 64 + mf * 16 + kc * 4;
      f32x4 v = acc[mf][nf];
      *(f32x4*)&cl[ocl * 132 + m0] = v;
    }
  }
  __syncthreads();
  for (int idx = t; idx < 128 * 128; idx += 512) {
    int ocl = idx >> 7, m = idx & 127;
    if (m < 121) {
      int oc = nh * 128 + ocl;
      p[((size_t)b * 256 + oc) * 121 + m] = cl[ocl * 132 + m] + bias[oc];
    }
  }
}

// ---------------- squash primary caps: p flat groups of 8 -------------------
__global__ __launch_bounds__(256) void squash_caps_k(const float* __restrict__ p,
    float* __restrict__ caps) {
  int tid = blockIdx.x * blockDim.x + threadIdx.x;
  const int total = NB * NCAPS;
  if (tid >= total) return;
  const float4* src = (const float4*)(p + (size_t)tid * 8);
  float4 a = src[0], b4 = src[1];
  float n2 = a.x * a.x + a.y * a.y + a.z * a.z + a.w * a.w +
             b4.x * b4.x + b4.y * b4.y + b4.z * b4.z + b4.w * b4.w;
  float nrm = sqrtf(n2);
  float scale = n2 / (1.0f + n2) / (nrm + 1e-8f);
  a.x *= scale; a.y *= scale; a.z *= scale; a.w *= scale;
  b4.x *= scale; b4.y *= scale; b4.z *= scale; b4.w *= scale;
  float4* dst = (float4*)(caps + (size_t)tid * 8);
  dst[0] = a; dst[1] = b4;
}

// ---------------- routing pass: s_part = sum_n softmax_o(osum.xh) * xh ------
__global__ __launch_bounds__(512) void route_k(const float* __restrict__ caps,
    const float* __restrict__ cw, const float* __restrict__ osum,
    float* __restrict__ spart) {
  int split = blockIdx.x;      // 0..63
  int btile = blockIdx.y;      // 0..3
  int t = threadIdx.x;         // 0..511
  int o = t & 15;
  int bl = t >> 4;             // 0..31
  int b = btile * 32 + bl;
  float os[16];
  const float* op = osum + (b * 16 + o) * 16;
#pragma unroll
  for (int i = 0; i < 16; i++) os[i] = op[i];
  float sacc[16];
#pragma unroll
  for (int i = 0; i < 16; i++) sacc[i] = 0.f;
  int nbeg = split * NPB;
  int nend = nbeg + NPB; if (nend > NCAPS) nend = NCAPS;
  for (int n = nbeg; n < nend; n++) {
    const float4* cp = (const float4*)(caps + ((size_t)b * NCAPS + n) * 8);
    float4 c0 = cp[0], c1 = cp[1];
    float xh[16];
    const float* wp = cw + (((size_t)o * NCAPS + n) * 16) * 8;
#pragma unroll
    for (int i = 0; i < 16; i++) {
      const float4* w4 = (const float4*)(wp + i * 8);
      float4 a = w4[0], bb = w4[1];
      xh[i] = a.x * c0.x + a.y * c0.y + a.z * c0.z + a.w * c0.w +
              bb.x * c1.x + bb.y * c1.y + bb.z * c1.z + bb.w * c1.w;
    }
    float blog = 0.f;
#pragma unroll
    for (int i = 0; i < 16; i++) blog += os[i] * xh[i];
    float m = blog;
#pragma unroll
    for (int d = 1; d < 16; d <<= 1) m = fmaxf(m, __shfl_xor(m, d));
    float e = __expf(blog - m);
    float ssum = e;
#pragma unroll
    for (int d = 1; d < 16; d <<= 1) ssum += __shfl_xor(ssum, d);
    float cc = e / ssum;
#pragma unroll
    for (int i = 0; i < 16; i++) sacc[i] += cc * xh[i];
  }
  float* sp = spart + (((size_t)split * NB + b) * 16 + o) * 16;
#pragma unroll
  for (int i = 0; i < 16; i++) sp[i] = sacc[i];
}

// ---------------- combine partials + squash + osum update -------------------
__global__ __launch_bounds__(256) void combine_squash_k(const float* __restrict__ spart,
    float* __restrict__ osum, float* __restrict__ outbuf, const float* __restrict__ y,
    float* __restrict__ masked, float* __restrict__ length_out, int last) {
  int tid = blockIdx.x * blockDim.x + threadIdx.x;   // 32768 = 128*16*16
  int i = tid & 15;
  int o = (tid >> 4) & 15;
  int b = tid >> 8;
  float s = 0.f;
  for (int k = 0; k < NSPLIT; k++) s += spart[k * 32768 + tid];
  float n2 = s * s;
#pragma unroll
  for (int d = 1; d < 16; d <<= 1) n2 += __shfl_xor(n2, d);
  float nrm = sqrtf(n2);
  float scale = n2 / (1.f + n2) / (nrm + 1e-8f);
  float ov = scale * s;
  outbuf[tid] = ov;
  osum[tid] += ov;
  if (last) {
    masked[tid] = ov * y[b * 16 + o];
    if (i == 0) length_out[b * 16 + o] = scale * nrm;
  }
}

// ---------------- decoder -----------------------------------------------------
__global__ __launch_bounds__(256) void dec1_k(const float* __restrict__ masked,
    const float* __restrict__ w1, const float* __restrict__ b1, float* __restrict__ r1) {
  int tid = blockIdx.x * blockDim.x + threadIdx.x;
  if (tid >= NB * D1) return;
  int j = tid % D1;
  int b = tid / D1;
  const float* mp = masked + b * 256;
  float acc = b1[j];
  for (int k = 0; k < 256; k++) acc += mp[k] * w1[k * D1 + j];
  r1[tid] = 1.f / (1.f + __expf(-acc));
}

__global__ __launch_bounds__(256) void dec2_k(const float* __restrict__ r1,
    const float* __restrict__ w2, const float* __restrict__ b2, float* __restrict__ r2) {
  int tid = blockIdx.x * blockDim.x + threadIdx.x;
  if (tid >= NB * D2) return;
  int j = tid % D2;
  int b = tid / D2;
  const float* rp = r1 + b * D1;
  float acc = b2[j];
  for (int k = 0; k < D1; k++) acc += rp[k] * w2[k * D2 + j];
  r2[tid] = 1.f / (1.f + __expf(-acc));
}

__global__ __launch_bounds__(256) void dec3_k(const float* __restrict__ r2,
    const float* __restrict__ w3, const float* __restrict__ b3, float* __restrict__ recon) {
  __shared__ float r2s[D2 * 64];
  int mt = blockIdx.x, bh = blockIdx.y;
  int t = threadIdx.x;
  int b0 = bh * 64;
  for (int idx = t; idx < D2 * 64; idx += 256) {
    int bb = idx / D2, k = idx - bb * D2;
    r2s[k * 64 + bb] = r2[(b0 + bb) * D2 + k];
  }
  __syncthreads();
  int moff = t & 63, bg = t >> 6;
  int m = mt * 64 + moff;
  if (m >= OUTPIX) return;
  float acc[16];
#pragma unroll
  for (int q = 0; q < 16; q++) acc[q] = 0.f;
  for (int k = 0; k < D2; k++) {
    float wv = w3[k * OUTPIX + m];
    const float4* r4 = (const float4*)&r2s[k * 64 + bg * 16];
#pragma unroll
    for (int v = 0; v < 4; v++) {
      float4 rv = r4[v];
      acc[v * 4 + 0] += wv * rv.x;
      acc[v * 4 + 1] += wv * rv.y;
      acc[v * 4 + 2] += wv * rv.z;
      acc[v * 4 + 3] += wv * rv.w;
    }
  }
  float bias = b3[m];
#pragma unroll
  for (int q = 0; q < 16; q++) {
    int b = b0 + bg * 16 + q;
    recon[(size_t)b * OUTPIX + m] = acc[q] + bias;
  }
}

extern "C" void kernel_launch(void* const* d_in, const int* in_sizes, int n_in,
                              void* d_out, int out_size, void* d_ws, size_t ws_size,
                              hipStream_t stream) {
  const float* x      = (const float*)d_in[0];
  const float* y      = (const float*)d_in[1];
  const float* conv1w = (const float*)d_in[2];
  const float* conv1b = (const float*)d_in[3];
  const float* gamma  = (const float*)d_in[4];
  const float* beta   = (const float*)d_in[5];
  const float* conv2w = (const float*)d_in[6];
  const float* conv2b = (const float*)d_in[7];
  const float* capsw  = (const float*)d_in[8];
  const float* w1     = (const float*)d_in[9];
  const float* b1     = (const float*)d_in[10];
  const float* w2     = (const float*)d_in[11];
  const float* b2     = (const float*)d_in[12];
  const float* w3     = (const float*)d_in[13];
  const float* b3     = (const float*)d_in[14];

  float* ws = (float*)d_ws;
  float* h      = ws;                    // 128*256*169   = 5537792
  float* p      = h + 5537792;           // 128*256*121   = 3964928
  float* caps   = p + 3964928;           // 128*3872*8    = 3964928
  float* mean   = caps + 3964928;        // 256
  float* istd   = mean + 256;            // 256
  float* osum   = istd + 256;            // 32768
  float* spart  = osum + 32768;          // 64*128*256    = 2097152
  float* outb   = spart + 2097152;       // 32768
  float* masked = outb + 32768;          // 32768
  float* r1     = masked + 32768;        // 128*328 = 41984
  float* r2     = r1 + 41984;            // 128*192 = 24576
  unsigned short* wpk = (unsigned short*)(r2 + 24576);   // 589824 bf16 = 294912 floats

  float* length_out = (float*)d_out;           // 2048
  float* recon      = (float*)d_out + 2048;    // 864000

  // conv stem
  {
    int total = NB * OC * H1;
    conv1_k<<<(total + 255) / 256, 256, 0, stream>>>(x, conv1w, conv1b, h);
  }
  bn_stats_k<<<OC, 256, 0, stream>>>(h, mean, istd);
  bn_apply_k<<<NB * OC, 256, 0, stream>>>(h, mean, istd, gamma, beta);

  pack_w2_k<<<589824 / 256, 256, 0, stream>>>(conv2w, wpk);
  conv2_mfma_k<<<256, 512, 0, stream>>>(h, wpk, conv2b, p);

  {
    int total = NB * NCAPS;
    squash_caps_k<<<(total + 255) / 256, 256, 0, stream>>>(p, caps);
  }

  // dynamic routing (3 iterations), osum = sum of previous outs
  hipMemsetAsync(osum, 0, 32768 * sizeof(float), stream);
  for (int it = 0; it < 3; ++it) {
    route_k<<<dim3(NSPLIT, 4), 512, 0, stream>>>(caps, capsw, osum, spart);
    combine_squash_k<<<128, 256, 0, stream>>>(spart, osum, outb, y, masked,
                                              length_out, it == 2 ? 1 : 0);
  }

  // decoder
  dec1_k<<<(NB * D1 + 255) / 256, 256, 0, stream>>>(masked, w1, b1, r1);
  dec2_k<<<(NB * D2 + 255) / 256, 256, 0, stream>>>(r1, w2, b2, r2);
  dec3_k<<<dim3((OUTPIX + 63) / 64, 2), 256, 0, stream>>>(r2, w3, b3, recon);
}

// Round 3
// 1450.005 us; speedup vs baseline: 1.8351x; 1.1689x over previous
//
#include <hip/hip_runtime.h>
#include <hip/hip_bf16.h>

// Sizes
#define NB 128
#define CIN 30
#define HW 15
#define OC 256
#define H1 13   // conv1 out
#define H2 11   // conv2 out
#define NCAPS 3872
#define IND 8
#define OUTD 16
#define CLS 16
#define D1 328
#define D2 192
#define OUTPIX 6750   // 30*15*15
#define NSPLIT 121
#define NPB 32        // 121*32 = 3872 exactly
#define RN 4          // n's staged per LDS round

typedef __attribute__((ext_vector_type(8))) short short8_t;
typedef __attribute__((ext_vector_type(4))) float f32x4;

__device__ inline unsigned bf16rne(float f) {
  unsigned u = __builtin_bit_cast(unsigned, f);
  return (u + 0x7FFF + ((u >> 16) & 1)) >> 16;
}

// ---------------- conv1: x[128,30,15,15] -> h[128,256,13,13] ----------------
__global__ __launch_bounds__(256) void conv1_k(const float* __restrict__ x,
    const float* __restrict__ w, const float* __restrict__ bias, float* __restrict__ h) {
  int tid = blockIdx.x * blockDim.x + threadIdx.x;
  const int total = NB * OC * H1;
  if (tid >= total) return;
  int oy = tid % H1;
  int q = tid / H1;          // b*256+oc
  int oc = q & 255;
  int b = q >> 8;
  float acc[H1];
  float bs = bias[oc];
#pragma unroll
  for (int i = 0; i < H1; i++) acc[i] = bs;
  const float* xb = x + b * CIN * HW * HW;
  const float* wb = w + oc * CIN * 9;
  for (int ic = 0; ic < CIN; ic++) {
    const float* xc = xb + ic * (HW * HW) + oy * HW;
    float wv[9];
#pragma unroll
    for (int t = 0; t < 9; t++) wv[t] = wb[ic * 9 + t];
#pragma unroll
    for (int ky = 0; ky < 3; ky++) {
      float xr[HW];
#pragma unroll
      for (int xx = 0; xx < HW; xx++) xr[xx] = xc[ky * HW + xx];
#pragma unroll
      for (int kx = 0; kx < 3; kx++) {
        float wvv = wv[ky * 3 + kx];
#pragma unroll
        for (int ox = 0; ox < H1; ox++) acc[ox] += xr[ox + kx] * wvv;
      }
    }
  }
  float* hp = h + q * (H1 * H1) + oy * H1;
#pragma unroll
  for (int ox = 0; ox < H1; ox++) hp[ox] = acc[ox];
}

// ---------------- BN stats: per-channel mean / invstd over B*13*13 ----------
__global__ __launch_bounds__(256) void bn_stats_k(const float* __restrict__ h,
    float* __restrict__ mean, float* __restrict__ istd) {
  int c = blockIdx.x;
  int t = threadIdx.x;
  float s = 0.f, s2 = 0.f;
  const int per = H1 * H1;               // 169
  for (int i = t; i < NB * per; i += 256) {
    int b = i / per, pos = i - b * per;
    float v = h[(b * OC + c) * per + pos];
    s += v; s2 += v * v;
  }
  __shared__ float ls[256], ls2[256];
  ls[t] = s; ls2[t] = s2; __syncthreads();
  for (int off = 128; off > 0; off >>= 1) {
    if (t < off) { ls[t] += ls[t + off]; ls2[t] += ls2[t + off]; }
    __syncthreads();
  }
  if (t == 0) {
    const float inv_n = 1.0f / (NB * per);
    float m = ls[0] * inv_n;
    float v = ls2[0] * inv_n - m * m;
    mean[c] = m;
    istd[c] = rsqrtf(v + 1e-5f);
  }
}

// ---------------- BN apply + relu (in place on h) ---------------------------
__global__ __launch_bounds__(256) void bn_apply_k(float* __restrict__ h,
    const float* __restrict__ mean, const float* __restrict__ istd,
    const float* __restrict__ gamma, const float* __restrict__ beta) {
  int bc = blockIdx.x;           // b*256+c
  int c = bc & 255;
  int t = threadIdx.x;
  if (t >= H1 * H1) return;
  float v = h[bc * (H1 * H1) + t];
  v = (v - mean[c]) * istd[c] * gamma[c] + beta[c];
  h[bc * (H1 * H1) + t] = fmaxf(v, 0.0f);
}

// ---------------- pack conv2 weights to MFMA layout -------------------------
// w[oc][ic][3][3] f32 -> wpk[(ky*3+kx)][icchunk(32)][oc(256)][8ic] bf16
__global__ __launch_bounds__(256) void pack_w2_k(const float* __restrict__ w,
    unsigned short* __restrict__ wpk) {
  int tid = blockIdx.x * blockDim.x + threadIdx.x;    // 589824
  int e = tid & 7;
  int oc = (tid >> 3) & 255;
  int icchunk = (tid >> 11) & 31;
  int kykx = tid >> 16;
  int ic = icchunk * 8 + e;
  wpk[tid] = (unsigned short)bf16rne(w[((size_t)oc * 256 + ic) * 9 + kykx]);
}

// ---------------- conv2 via bf16 MFMA implicit GEMM -------------------------
__global__ __launch_bounds__(512, 1) void conv2_mfma_k(
    const float* __restrict__ h, const unsigned short* __restrict__ wpk,
    const float* __restrict__ bias, float* __restrict__ p) {
  __shared__ char smem[169 * 544];       // 91936 B; reused for C transpose
  unsigned* hs32 = (unsigned*)smem;      // [pix][136] u32  (272 bf16, 16 pad)
  int bid = blockIdx.x;                  // 0..255
  int b = bid >> 1;
  int nh = bid & 1;                      // oc half
  int t = threadIdx.x;
  int l = t & 63, wid = t >> 6;

  {
    const float* hb = h + (size_t)b * 256 * 169;
    for (int icp = wid; icp < 128; icp += 8) {
      const float* s0 = hb + (size_t)icp * 2 * 169;
#pragma unroll
      for (int pb = 0; pb < 3; pb++) {
        int pix = pb * 64 + l;
        if (pix < 169) {
          unsigned u0 = bf16rne(s0[pix]);
          unsigned u1 = bf16rne(s0[169 + pix]);
          hs32[pix * 136 + icp] = u0 | (u1 << 16);
        }
      }
    }
  }
  __syncthreads();

  int wm = wid & 1;        // m offset wm*64
  int wn = wid >> 1;       // n offset wn*32
  int row = l & 15, kc = l >> 4;
  int ocb = nh * 128 + wn * 32;

  int abase[4];
#pragma unroll
  for (int mf = 0; mf < 4; mf++) {
    int m = wm * 64 + mf * 16 + row;
    int p0 = (m < 121) ? ((m / 11) * 13 + (m % 11)) : 0;
    abase[mf] = p0 * 544 + kc * 16;
  }

  f32x4 acc[4][2];
#pragma unroll
  for (int mf = 0; mf < 4; mf++)
#pragma unroll
    for (int nf = 0; nf < 2; nf++)
      acc[mf][nf] = (f32x4){0.f, 0.f, 0.f, 0.f};

  const size_t lanebase = ((size_t)kc * 256 + ocb + row) * 8;
  const char* lds_base = (const char*)smem;

  for (int ky = 0; ky < 3; ky++) {
    for (int kx = 0; kx < 3; kx++) {
      int r = ky * 3 + kx;
      int koff = (ky * 13 + kx) * 544;
#pragma unroll
      for (int ks = 0; ks < 8; ks++) {
        short8_t bfr[2];
#pragma unroll
        for (int nf = 0; nf < 2; nf++) {
          size_t idx = lanebase + (size_t)(r * 32 + ks * 4) * 2048 + nf * 128;
          bfr[nf] = *(const short8_t*)(wpk + idx);
        }
        short8_t af[4];
#pragma unroll
        for (int mf = 0; mf < 4; mf++)
          af[mf] = *(const short8_t*)(lds_base + (abase[mf] + koff + ks * 64));
#pragma unroll
        for (int mf = 0; mf < 4; mf++)
#pragma unroll
          for (int nf = 0; nf < 2; nf++)
            acc[mf][nf] = __builtin_amdgcn_mfma_f32_16x16x32_bf16(
                af[mf], bfr[nf], acc[mf][nf], 0, 0, 0);
      }
    }
  }

  __syncthreads();
  float* cl = (float*)smem;              // [ocl 0..127][132 m-pad]
#pragma unroll
  for (int nf = 0; nf < 2; nf++) {
    int ocl = wn * 32 + nf * 16 + row;
#pragma unroll
    for (int mf = 0; mf < 4; mf++) {
      int m0 = wm * 64 + mf * 16 + kc * 4;
      f32x4 v = acc[mf][nf];
      *(f32x4*)&cl[ocl * 132 + m0] = v;
    }
  }
  __syncthreads();
  for (int idx = t; idx < 128 * 128; idx += 512) {
    int ocl = idx >> 7, m = idx & 127;
    if (m < 121) {
      int oc = nh * 128 + ocl;
      p[((size_t)b * 256 + oc) * 121 + m] = cl[ocl * 132 + m] + bias[oc];
    }
  }
}

// ---------------- squash primary caps ---------------------------------------
__global__ __launch_bounds__(256) void squash_caps_k(const float* __restrict__ p,
    float* __restrict__ caps) {
  int tid = blockIdx.x * blockDim.x + threadIdx.x;
  const int total = NB * NCAPS;
  if (tid >= total) return;
  const float4* src = (const float4*)(p + (size_t)tid * 8);
  float4 a = src[0], b4 = src[1];
  float n2 = a.x * a.x + a.y * a.y + a.z * a.z + a.w * a.w +
             b4.x * b4.x + b4.y * b4.y + b4.z * b4.z + b4.w * b4.w;
  float nrm = sqrtf(n2);
  float scale = n2 / (1.0f + n2) / (nrm + 1e-8f);
  a.x *= scale; a.y *= scale; a.z *= scale; a.w *= scale;
  b4.x *= scale; b4.y *= scale; b4.z *= scale; b4.w *= scale;
  float4* dst = (float4*)(caps + (size_t)tid * 8);
  dst[0] = a; dst[1] = b4;
}

// ---------------- pack caps_w: cw[o][n][i][j] -> Wp[n][o][i][j] -------------
__global__ __launch_bounds__(256) void pack_cw_k(const float* __restrict__ cw,
    float* __restrict__ Wp) {
  int idx = blockIdx.x * blockDim.x + threadIdx.x;   // 7933952
  int j = idx & 7;
  int i = (idx >> 3) & 15;
  int o = (idx >> 7) & 15;
  int n = idx >> 11;
  Wp[idx] = cw[(((size_t)o * NCAPS + n) * 16 + i) * 8 + j];
}

// ---------------- routing pass v2: LDS-staged W -----------------------------
// block = (split, btile): 512 thr = 32 b x 16 o. RN n's staged per round.
// LDS layout wl[nl][o][132] (128 data + 4 pad) -> 2-way-only bank aliasing.
__global__ __launch_bounds__(512) void route_k(const float* __restrict__ caps,
    const float* __restrict__ Wp, const float* __restrict__ osum,
    float* __restrict__ spart) {
  __shared__ float wl[RN * 16 * 132];    // 33792 B
  int split = blockIdx.x;      // 0..120
  int btile = blockIdx.y;      // 0..3
  int t = threadIdx.x;         // 0..511
  int o = t & 15;
  int bl = t >> 4;             // 0..31
  int b = btile * 32 + bl;
  float os[16];
  const float* op = osum + (b * 16 + o) * 16;
#pragma unroll
  for (int i = 0; i < 16; i++) os[i] = op[i];
  float sacc[16];
#pragma unroll
  for (int i = 0; i < 16; i++) sacc[i] = 0.f;

  int nbeg = split * NPB;
  const float* wlo = &wl[o * 132];
  for (int r = 0; r < NPB / RN; r++) {
    int n0 = nbeg + r * RN;
    // ---- cooperative stage: RN*2048 floats contiguous from Wp
    __syncthreads();
    const float4* src = (const float4*)(Wp + (size_t)n0 * 2048);
#pragma unroll
    for (int k = 0; k < RN; k++) {
      int g = t * 4 + k * 2048;          // float index
      float4 v = src[t + k * 512];
      int nl = g >> 11, rem = g & 2047;
      int o2 = rem >> 7, rest = rem & 127;
      *(float4*)&wl[(nl * 16 + o2) * 132 + rest] = v;
    }
    __syncthreads();
#pragma unroll
    for (int nl = 0; nl < RN; nl++) {
      int n = n0 + nl;
      const float4* cp = (const float4*)(caps + ((size_t)b * NCAPS + n) * 8);
      float4 c0 = cp[0], c1 = cp[1];
      const float* wp = wlo + nl * (16 * 132);
      float xh[16];
#pragma unroll
      for (int i = 0; i < 16; i++) {
        f32x4 a = *(const f32x4*)(wp + i * 8);
        f32x4 bb = *(const f32x4*)(wp + i * 8 + 4);
        xh[i] = a.x * c0.x + a.y * c0.y + a.z * c0.z + a.w * c0.w +
                bb.x * c1.x + bb.y * c1.y + bb.z * c1.z + bb.w * c1.w;
      }
      float blog = 0.f;
#pragma unroll
      for (int i = 0; i < 16; i++) blog += os[i] * xh[i];
      float m = blog;
#pragma unroll
      for (int d = 1; d < 16; d <<= 1) m = fmaxf(m, __shfl_xor(m, d));
      float e = __expf(blog - m);
      float ssum = e;
#pragma unroll
      for (int d = 1; d < 16; d <<= 1) ssum += __shfl_xor(ssum, d);
      float cc = e / ssum;
#pragma unroll
      for (int i = 0; i < 16; i++) sacc[i] += cc * xh[i];
    }
  }
  float* sp = spart + (((size_t)split * NB + b) * 16 + o) * 16;
#pragma unroll
  for (int i = 0; i < 16; i++) sp[i] = sacc[i];
}

// ---------------- combine partials + squash + osum update -------------------
__global__ __launch_bounds__(256) void combine_squash_k(const float* __restrict__ spart,
    float* __restrict__ osum, float* __restrict__ outbuf, const float* __restrict__ y,
    float* __restrict__ masked, float* __restrict__ length_out, int last) {
  int tid = blockIdx.x * blockDim.x + threadIdx.x;   // 32768 = 128*16*16
  int i = tid & 15;
  int o = (tid >> 4) & 15;
  int b = tid >> 8;
  float s = 0.f;
  for (int k = 0; k < NSPLIT; k++) s += spart[k * 32768 + tid];
  float n2 = s * s;
#pragma unroll
  for (int d = 1; d < 16; d <<= 1) n2 += __shfl_xor(n2, d);
  float nrm = sqrtf(n2);
  float scale = n2 / (1.f + n2) / (nrm + 1e-8f);
  float ov = scale * s;
  outbuf[tid] = ov;
  osum[tid] += ov;
  if (last) {
    masked[tid] = ov * y[b * 16 + o];
    if (i == 0) length_out[b * 16 + o] = scale * nrm;
  }
}

// ---------------- decoder -----------------------------------------------------
__global__ __launch_bounds__(256) void dec1_k(const float* __restrict__ masked,
    const float* __restrict__ w1, const float* __restrict__ b1, float* __restrict__ r1) {
  int tid = blockIdx.x * blockDim.x + threadIdx.x;
  if (tid >= NB * D1) return;
  int j = tid % D1;
  int b = tid / D1;
  const float* mp = masked + b * 256;
  float acc = b1[j];
  for (int k = 0; k < 256; k++) acc += mp[k] * w1[k * D1 + j];
  r1[tid] = 1.f / (1.f + __expf(-acc));
}

__global__ __launch_bounds__(256) void dec2_k(const float* __restrict__ r1,
    const float* __restrict__ w2, const float* __restrict__ b2, float* __restrict__ r2) {
  int tid = blockIdx.x * blockDim.x + threadIdx.x;
  if (tid >= NB * D2) return;
  int j = tid % D2;
  int b = tid / D2;
  const float* rp = r1 + b * D1;
  float acc = b2[j];
  for (int k = 0; k < D1; k++) acc += rp[k] * w2[k * D2 + j];
  r2[tid] = 1.f / (1.f + __expf(-acc));
}

__global__ __launch_bounds__(256) void dec3_k(const float* __restrict__ r2,
    const float* __restrict__ w3, const float* __restrict__ b3, float* __restrict__ recon) {
  __shared__ float r2s[D2 * 64];
  int mt = blockIdx.x, bh = blockIdx.y;
  int t = threadIdx.x;
  int b0 = bh * 64;
  for (int idx = t; idx < D2 * 64; idx += 256) {
    int bb = idx / D2, k = idx - bb * D2;
    r2s[k * 64 + bb] = r2[(b0 + bb) * D2 + k];
  }
  __syncthreads();
  int moff = t & 63, bg = t >> 6;
  int m = mt * 64 + moff;
  if (m >= OUTPIX) return;
  float acc[16];
#pragma unroll
  for (int q = 0; q < 16; q++) acc[q] = 0.f;
  for (int k = 0; k < D2; k++) {
    float wv = w3[k * OUTPIX + m];
    const float4* r4 = (const float4*)&r2s[k * 64 + bg * 16];
#pragma unroll
    for (int v = 0; v < 4; v++) {
      float4 rv = r4[v];
      acc[v * 4 + 0] += wv * rv.x;
      acc[v * 4 + 1] += wv * rv.y;
      acc[v * 4 + 2] += wv * rv.z;
      acc[v * 4 + 3] += wv * rv.w;
    }
  }
  float bias = b3[m];
#pragma unroll
  for (int q = 0; q < 16; q++) {
    int b = b0 + bg * 16 + q;
    recon[(size_t)b * OUTPIX + m] = acc[q] + bias;
  }
}

extern "C" void kernel_launch(void* const* d_in, const int* in_sizes, int n_in,
                              void* d_out, int out_size, void* d_ws, size_t ws_size,
                              hipStream_t stream) {
  const float* x      = (const float*)d_in[0];
  const float* y      = (const float*)d_in[1];
  const float* conv1w = (const float*)d_in[2];
  const float* conv1b = (const float*)d_in[3];
  const float* gamma  = (const float*)d_in[4];
  const float* beta   = (const float*)d_in[5];
  const float* conv2w = (const float*)d_in[6];
  const float* conv2b = (const float*)d_in[7];
  const float* capsw  = (const float*)d_in[8];
  const float* w1     = (const float*)d_in[9];
  const float* b1     = (const float*)d_in[10];
  const float* w2     = (const float*)d_in[11];
  const float* b2     = (const float*)d_in[12];
  const float* w3     = (const float*)d_in[13];
  const float* b3     = (const float*)d_in[14];

  float* ws = (float*)d_ws;
  float* h      = ws;                    // 128*256*169   = 5537792
  float* p      = h + 5537792;           // 128*256*121   = 3964928
  float* caps   = p + 3964928;           // 128*3872*8    = 3964928
  float* mean   = caps + 3964928;        // 256
  float* istd   = mean + 256;            // 256
  float* osum   = istd + 256;            // 32768
  float* spart  = osum + 32768;          // 121*32768     = 3964928
  float* outb   = spart + 3964928;       // 32768
  float* masked = outb + 32768;          // 32768
  float* r1     = masked + 32768;        // 128*328 = 41984
  float* r2     = r1 + 41984;            // 128*192 = 24576
  unsigned short* wpk = (unsigned short*)(r2 + 24576);   // 589824 bf16
  // Wp aliases h+p region (dead after squash_caps): 7933952 floats <= 9502720
  float* Wp     = ws;

  float* length_out = (float*)d_out;           // 2048
  float* recon      = (float*)d_out + 2048;    // 864000

  // conv stem
  {
    int total = NB * OC * H1;
    conv1_k<<<(total + 255) / 256, 256, 0, stream>>>(x, conv1w, conv1b, h);
  }
  bn_stats_k<<<OC, 256, 0, stream>>>(h, mean, istd);
  bn_apply_k<<<NB * OC, 256, 0, stream>>>(h, mean, istd, gamma, beta);

  pack_w2_k<<<589824 / 256, 256, 0, stream>>>(conv2w, wpk);
  conv2_mfma_k<<<256, 512, 0, stream>>>(h, wpk, conv2b, p);

  {
    int total = NB * NCAPS;
    squash_caps_k<<<(total + 255) / 256, 256, 0, stream>>>(p, caps);
  }

  // h & p are dead now -> pack caps_w into their region
  pack_cw_k<<<7933952 / 256, 256, 0, stream>>>(capsw, Wp);

  // dynamic routing (3 iterations), osum = sum of previous outs
  hipMemsetAsync(osum, 0, 32768 * sizeof(float), stream);
  for (int it = 0; it < 3; ++it) {
    route_k<<<dim3(NSPLIT, 4), 512, 0, stream>>>(caps, Wp, osum, spart);
    combine_squash_k<<<128, 256, 0, stream>>>(spart, osum, outb, y, masked,
                                              length_out, it == 2 ? 1 : 0);
  }

  // decoder
  dec1_k<<<(NB * D1 + 255) / 256, 256, 0, stream>>>(masked, w1, b1, r1);
  dec2_k<<<(NB * D2 + 255) / 256, 256, 0, stream>>>(r1, w2, b2, r2);
  dec3_k<<<dim3((OUTPIX + 63) / 64, 2), 256, 0, stream>>>(r2, w3, b3, recon);
}

// Round 4
// 1248.459 us; speedup vs baseline: 2.1313x; 1.1614x over previous
//
#include <hip/hip_runtime.h>
#include <hip/hip_bf16.h>

// Sizes
#define NB 128
#define CIN 30
#define HW 15
#define OC 256
#define H1 13   // conv1 out
#define H2 11   // conv2 out
#define NCAPS 3872
#define IND 8
#define OUTD 16
#define CLS 16
#define D1 328
#define D2 192
#define OUTPIX 6750   // 30*15*15
#define NSPLIT 121
#define NPB 32        // 121*32 = 3872 exactly
#define RN 2          // n's per LDS buffer round
#define ROUNDS 16     // NPB/RN

typedef __attribute__((ext_vector_type(8))) short short8_t;
typedef __attribute__((ext_vector_type(4))) float f32x4;

__device__ inline unsigned bf16rne(float f) {
  unsigned u = __builtin_bit_cast(unsigned, f);
  return (u + 0x7FFF + ((u >> 16) & 1)) >> 16;
}

// ---------------- conv1: x[128,30,15,15] -> h[128,256,13,13] ----------------
__global__ __launch_bounds__(256) void conv1_k(const float* __restrict__ x,
    const float* __restrict__ w, const float* __restrict__ bias, float* __restrict__ h) {
  int tid = blockIdx.x * blockDim.x + threadIdx.x;
  const int total = NB * OC * H1;
  if (tid >= total) return;
  int oy = tid % H1;
  int q = tid / H1;          // b*256+oc
  int oc = q & 255;
  int b = q >> 8;
  float acc[H1];
  float bs = bias[oc];
#pragma unroll
  for (int i = 0; i < H1; i++) acc[i] = bs;
  const float* xb = x + b * CIN * HW * HW;
  const float* wb = w + oc * CIN * 9;
  for (int ic = 0; ic < CIN; ic++) {
    const float* xc = xb + ic * (HW * HW) + oy * HW;
    float wv[9];
#pragma unroll
    for (int t = 0; t < 9; t++) wv[t] = wb[ic * 9 + t];
#pragma unroll
    for (int ky = 0; ky < 3; ky++) {
      float xr[HW];
#pragma unroll
      for (int xx = 0; xx < HW; xx++) xr[xx] = xc[ky * HW + xx];
#pragma unroll
      for (int kx = 0; kx < 3; kx++) {
        float wvv = wv[ky * 3 + kx];
#pragma unroll
        for (int ox = 0; ox < H1; ox++) acc[ox] += xr[ox + kx] * wvv;
      }
    }
  }
  float* hp = h + q * (H1 * H1) + oy * H1;
#pragma unroll
  for (int ox = 0; ox < H1; ox++) hp[ox] = acc[ox];
}

// ---------------- BN stats ---------------------------------------------------
__global__ __launch_bounds__(256) void bn_stats_k(const float* __restrict__ h,
    float* __restrict__ mean, float* __restrict__ istd) {
  int c = blockIdx.x;
  int t = threadIdx.x;
  float s = 0.f, s2 = 0.f;
  const int per = H1 * H1;               // 169
  for (int i = t; i < NB * per; i += 256) {
    int b = i / per, pos = i - b * per;
    float v = h[(b * OC + c) * per + pos];
    s += v; s2 += v * v;
  }
  __shared__ float ls[256], ls2[256];
  ls[t] = s; ls2[t] = s2; __syncthreads();
  for (int off = 128; off > 0; off >>= 1) {
    if (t < off) { ls[t] += ls[t + off]; ls2[t] += ls2[t + off]; }
    __syncthreads();
  }
  if (t == 0) {
    const float inv_n = 1.0f / (NB * per);
    float m = ls[0] * inv_n;
    float v = ls2[0] * inv_n - m * m;
    mean[c] = m;
    istd[c] = rsqrtf(v + 1e-5f);
  }
}

// ---------------- BN apply + relu -------------------------------------------
__global__ __launch_bounds__(256) void bn_apply_k(float* __restrict__ h,
    const float* __restrict__ mean, const float* __restrict__ istd,
    const float* __restrict__ gamma, const float* __restrict__ beta) {
  int bc = blockIdx.x;           // b*256+c
  int c = bc & 255;
  int t = threadIdx.x;
  if (t >= H1 * H1) return;
  float v = h[bc * (H1 * H1) + t];
  v = (v - mean[c]) * istd[c] * gamma[c] + beta[c];
  h[bc * (H1 * H1) + t] = fmaxf(v, 0.0f);
}

// ---------------- pack conv2 weights to MFMA layout -------------------------
__global__ __launch_bounds__(256) void pack_w2_k(const float* __restrict__ w,
    unsigned short* __restrict__ wpk) {
  int tid = blockIdx.x * blockDim.x + threadIdx.x;    // 589824
  int e = tid & 7;
  int oc = (tid >> 3) & 255;
  int icchunk = (tid >> 11) & 31;
  int kykx = tid >> 16;
  int ic = icchunk * 8 + e;
  wpk[tid] = (unsigned short)bf16rne(w[((size_t)oc * 256 + ic) * 9 + kykx]);
}

// ---------------- conv2 via bf16 MFMA implicit GEMM -------------------------
__global__ __launch_bounds__(512, 1) void conv2_mfma_k(
    const float* __restrict__ h, const unsigned short* __restrict__ wpk,
    const float* __restrict__ bias, float* __restrict__ p) {
  __shared__ char smem[169 * 544];       // 91936 B; reused for C transpose
  unsigned* hs32 = (unsigned*)smem;      // [pix][136] u32  (272 bf16, 16 pad)
  int bid = blockIdx.x;                  // 0..255
  int b = bid >> 1;
  int nh = bid & 1;                      // oc half
  int t = threadIdx.x;
  int l = t & 63, wid = t >> 6;

  {
    const float* hb = h + (size_t)b * 256 * 169;
    for (int icp = wid; icp < 128; icp += 8) {
      const float* s0 = hb + (size_t)icp * 2 * 169;
#pragma unroll
      for (int pb = 0; pb < 3; pb++) {
        int pix = pb * 64 + l;
        if (pix < 169) {
          unsigned u0 = bf16rne(s0[pix]);
          unsigned u1 = bf16rne(s0[169 + pix]);
          hs32[pix * 136 + icp] = u0 | (u1 << 16);
        }
      }
    }
  }
  __syncthreads();

  int wm = wid & 1;        // m offset wm*64
  int wn = wid >> 1;       // n offset wn*32
  int row = l & 15, kc = l >> 4;
  int ocb = nh * 128 + wn * 32;

  int abase[4];
#pragma unroll
  for (int mf = 0; mf < 4; mf++) {
    int m = wm * 64 + mf * 16 + row;
    int p0 = (m < 121) ? ((m / 11) * 13 + (m % 11)) : 0;
    abase[mf] = p0 * 544 + kc * 16;
  }

  f32x4 acc[4][2];
#pragma unroll
  for (int mf = 0; mf < 4; mf++)
#pragma unroll
    for (int nf = 0; nf < 2; nf++)
      acc[mf][nf] = (f32x4){0.f, 0.f, 0.f, 0.f};

  const size_t lanebase = ((size_t)kc * 256 + ocb + row) * 8;
  const char* lds_base = (const char*)smem;

  for (int ky = 0; ky < 3; ky++) {
    for (int kx = 0; kx < 3; kx++) {
      int r = ky * 3 + kx;
      int koff = (ky * 13 + kx) * 544;
#pragma unroll
      for (int ks = 0; ks < 8; ks++) {
        short8_t bfr[2];
#pragma unroll
        for (int nf = 0; nf < 2; nf++) {
          size_t idx = lanebase + (size_t)(r * 32 + ks * 4) * 2048 + nf * 128;
          bfr[nf] = *(const short8_t*)(wpk + idx);
        }
        short8_t af[4];
#pragma unroll
        for (int mf = 0; mf < 4; mf++)
          af[mf] = *(const short8_t*)(lds_base + (abase[mf] + koff + ks * 64));
#pragma unroll
        for (int mf = 0; mf < 4; mf++)
#pragma unroll
          for (int nf = 0; nf < 2; nf++)
            acc[mf][nf] = __builtin_amdgcn_mfma_f32_16x16x32_bf16(
                af[mf], bfr[nf], acc[mf][nf], 0, 0, 0);
      }
    }
  }

  __syncthreads();
  float* cl = (float*)smem;              // [ocl 0..127][132 m-pad]
#pragma unroll
  for (int nf = 0; nf < 2; nf++) {
    int ocl = wn * 32 + nf * 16 + row;
#pragma unroll
    for (int mf = 0; mf < 4; mf++) {
      int m0 = wm * 64 + mf * 16 + kc * 4;
      f32x4 v = acc[mf][nf];
      *(f32x4*)&cl[ocl * 132 + m0] = v;
    }
  }
  __syncthreads();
  for (int idx = t; idx < 128 * 128; idx += 512) {
    int ocl = idx >> 7, m = idx & 127;
    if (m < 121) {
      int oc = nh * 128 + ocl;
      p[((size_t)b * 256 + oc) * 121 + m] = cl[ocl * 132 + m] + bias[oc];
    }
  }
}

// ---------------- squash primary caps ---------------------------------------
__global__ __launch_bounds__(256) void squash_caps_k(const float* __restrict__ p,
    float* __restrict__ caps) {
  int tid = blockIdx.x * blockDim.x + threadIdx.x;
  const int total = NB * NCAPS;
  if (tid >= total) return;
  const float4* src = (const float4*)(p + (size_t)tid * 8);
  float4 a = src[0], b4 = src[1];
  float n2 = a.x * a.x + a.y * a.y + a.z * a.z + a.w * a.w +
             b4.x * b4.x + b4.y * b4.y + b4.z * b4.z + b4.w * b4.w;
  float nrm = sqrtf(n2);
  float scale = n2 / (1.0f + n2) / (nrm + 1e-8f);
  a.x *= scale; a.y *= scale; a.z *= scale; a.w *= scale;
  b4.x *= scale; b4.y *= scale; b4.z *= scale; b4.w *= scale;
  float4* dst = (float4*)(caps + (size_t)tid * 8);
  dst[0] = a; dst[1] = b4;
}

// ---------------- pack caps_w: cw[o][n][i][j] -> Wp[n][o][i][j] -------------
__global__ __launch_bounds__(256) void pack_cw_k(const float* __restrict__ cw,
    float* __restrict__ Wp) {
  int idx = blockIdx.x * blockDim.x + threadIdx.x;   // 7933952
  int j = idx & 7;
  int i = (idx >> 3) & 15;
  int o = (idx >> 7) & 15;
  int n = idx >> 11;
  Wp[idx] = cw[(((size_t)o * NCAPS + n) * 16 + i) * 8 + j];
}

// ---------------- routing pass v3: double-buffered LDS, 256-thr blocks ------
// block = one of 968 (split 0..120 x btile 0..7): 256 thr = 16 b x 16 o.
// LDS wl[2 buf][2 n][16 o][132 pad]; one barrier per 2-n round.
// __launch_bounds__(256,3): allow ~170 VGPR so xh/sacc/os do NOT spill
// (round-3 spill was 812 MB of scratch writes = the real bottleneck).
__global__ __launch_bounds__(256, 3) void route_k(const float* __restrict__ caps,
    const float* __restrict__ Wp, const float* __restrict__ osum,
    float* __restrict__ spart) {
  __shared__ float wl[2][RN * 16 * 132];   // 33792 B
  int id = blockIdx.x;                     // 0..967
  // chunked XCD swizzle: s = (id%8)*121 + id/8 -> same split's btiles adjacent
  int s = (id & 7) * 121 + (id >> 3);
  int split = s >> 3;                      // 0..120
  int btile = s & 7;                       // 0..7
  int t = threadIdx.x;                     // 0..255
  int o = t & 15;
  int bl = t >> 4;                         // 0..15
  int b = btile * 16 + bl;

  float os[16];
  const float* op = osum + (b * 16 + o) * 16;
#pragma unroll
  for (int i = 0; i < 16; i++) os[i] = op[i];
  float sacc[16];
#pragma unroll
  for (int i = 0; i < 16; i++) sacc[i] = 0.f;

  int nbeg = split * NPB;
  const float4* src = (const float4*)(Wp + (size_t)nbeg * 2048);

  // destination rows for this thread's 4 staged float4s: q -> row (nl*16+o2)
  int srow[4];
  int scol = (4 * t) & 127;
#pragma unroll
  for (int q = 0; q < 4; q++)
    srow[q] = ((q >> 1) * 16 + (q & 1) * 8 + (t >> 5)) * 132;

  // prologue: stage round 0 into buf 0
  {
    float4 v[4];
#pragma unroll
    for (int q = 0; q < 4; q++) v[q] = src[q * 256 + t];
#pragma unroll
    for (int q = 0; q < 4; q++) *(float4*)&wl[0][srow[q] + scol] = v[q];
  }
  __syncthreads();

  for (int r = 0; r < ROUNDS; r++) {
    float4 nv[4];
    if (r < ROUNDS - 1) {
#pragma unroll
      for (int q = 0; q < 4; q++) nv[q] = src[(r + 1) * 1024 + q * 256 + t];
    }
    const float* wlb = wl[r & 1];
    int n0 = nbeg + r * RN;
#pragma unroll
    for (int nl = 0; nl < RN; nl++) {
      int n = n0 + nl;
      const float4* cp = (const float4*)(caps + ((size_t)b * NCAPS + n) * 8);
      float4 c0 = cp[0], c1 = cp[1];
      const float* wp = wlb + nl * (16 * 132) + o * 132;
      float xh[16];
#pragma unroll
      for (int i = 0; i < 16; i++) {
        f32x4 a = *(const f32x4*)(wp + i * 8);
        f32x4 bb = *(const f32x4*)(wp + i * 8 + 4);
        xh[i] = a.x * c0.x + a.y * c0.y + a.z * c0.z + a.w * c0.w +
                bb.x * c1.x + bb.y * c1.y + bb.z * c1.z + bb.w * c1.w;
      }
      float blog = 0.f;
#pragma unroll
      for (int i = 0; i < 16; i++) blog += os[i] * xh[i];
      float m = blog;
#pragma unroll
      for (int d = 1; d < 16; d <<= 1) m = fmaxf(m, __shfl_xor(m, d));
      float e = __expf(blog - m);
      float ssum = e;
#pragma unroll
      for (int d = 1; d < 16; d <<= 1) ssum += __shfl_xor(ssum, d);
      float cc = e / ssum;
#pragma unroll
      for (int i = 0; i < 16; i++) sacc[i] += cc * xh[i];
    }
    if (r < ROUNDS - 1) {
      float* dst = wl[(r + 1) & 1];
#pragma unroll
      for (int q = 0; q < 4; q++) *(float4*)&dst[srow[q] + scol] = nv[q];
      __syncthreads();
    }
  }
  float* sp = spart + (((size_t)split * NB + b) * 16 + o) * 16;
#pragma unroll
  for (int i = 0; i < 16; i++) sp[i] = sacc[i];
}

// ---------------- combine partials + squash + osum update -------------------
__global__ __launch_bounds__(256) void combine_squash_k(const float* __restrict__ spart,
    float* __restrict__ osum, float* __restrict__ outbuf, const float* __restrict__ y,
    float* __restrict__ masked, float* __restrict__ length_out, int last) {
  int tid = blockIdx.x * blockDim.x + threadIdx.x;   // 32768 = 128*16*16
  int i = tid & 15;
  int o = (tid >> 4) & 15;
  int b = tid >> 8;
  float s = 0.f;
  for (int k = 0; k < NSPLIT; k++) s += spart[k * 32768 + tid];
  float n2 = s * s;
#pragma unroll
  for (int d = 1; d < 16; d <<= 1) n2 += __shfl_xor(n2, d);
  float nrm = sqrtf(n2);
  float scale = n2 / (1.f + n2) / (nrm + 1e-8f);
  float ov = scale * s;
  outbuf[tid] = ov;
  osum[tid] += ov;
  if (last) {
    masked[tid] = ov * y[b * 16 + o];
    if (i == 0) length_out[b * 16 + o] = scale * nrm;
  }
}

// ---------------- decoder -----------------------------------------------------
__global__ __launch_bounds__(256) void dec1_k(const float* __restrict__ masked,
    const float* __restrict__ w1, const float* __restrict__ b1, float* __restrict__ r1) {
  int tid = blockIdx.x * blockDim.x + threadIdx.x;
  if (tid >= NB * D1) return;
  int j = tid % D1;
  int b = tid / D1;
  const float* mp = masked + b * 256;
  float acc = b1[j];
  for (int k = 0; k < 256; k++) acc += mp[k] * w1[k * D1 + j];
  r1[tid] = 1.f / (1.f + __expf(-acc));
}

__global__ __launch_bounds__(256) void dec2_k(const float* __restrict__ r1,
    const float* __restrict__ w2, const float* __restrict__ b2, float* __restrict__ r2) {
  int tid = blockIdx.x * blockDim.x + threadIdx.x;
  if (tid >= NB * D2) return;
  int j = tid % D2;
  int b = tid / D2;
  const float* rp = r1 + b * D1;
  float acc = b2[j];
  for (int k = 0; k < D1; k++) acc += rp[k] * w2[k * D2 + j];
  r2[tid] = 1.f / (1.f + __expf(-acc));
}

__global__ __launch_bounds__(256) void dec3_k(const float* __restrict__ r2,
    const float* __restrict__ w3, const float* __restrict__ b3, float* __restrict__ recon) {
  __shared__ float r2s[D2 * 64];
  int mt = blockIdx.x, bh = blockIdx.y;
  int t = threadIdx.x;
  int b0 = bh * 64;
  for (int idx = t; idx < D2 * 64; idx += 256) {
    int bb = idx / D2, k = idx - bb * D2;
    r2s[k * 64 + bb] = r2[(b0 + bb) * D2 + k];
  }
  __syncthreads();
  int moff = t & 63, bg = t >> 6;
  int m = mt * 64 + moff;
  if (m >= OUTPIX) return;
  float acc[16];
#pragma unroll
  for (int q = 0; q < 16; q++) acc[q] = 0.f;
  for (int k = 0; k < D2; k++) {
    float wv = w3[k * OUTPIX + m];
    const float4* r4 = (const float4*)&r2s[k * 64 + bg * 16];
#pragma unroll
    for (int v = 0; v < 4; v++) {
      float4 rv = r4[v];
      acc[v * 4 + 0] += wv * rv.x;
      acc[v * 4 + 1] += wv * rv.y;
      acc[v * 4 + 2] += wv * rv.z;
      acc[v * 4 + 3] += wv * rv.w;
    }
  }
  float bias = b3[m];
#pragma unroll
  for (int q = 0; q < 16; q++) {
    int b = b0 + bg * 16 + q;
    recon[(size_t)b * OUTPIX + m] = acc[q] + bias;
  }
}

extern "C" void kernel_launch(void* const* d_in, const int* in_sizes, int n_in,
                              void* d_out, int out_size, void* d_ws, size_t ws_size,
                              hipStream_t stream) {
  const float* x      = (const float*)d_in[0];
  const float* y      = (const float*)d_in[1];
  const float* conv1w = (const float*)d_in[2];
  const float* conv1b = (const float*)d_in[3];
  const float* gamma  = (const float*)d_in[4];
  const float* beta   = (const float*)d_in[5];
  const float* conv2w = (const float*)d_in[6];
  const float* conv2b = (const float*)d_in[7];
  const float* capsw  = (const float*)d_in[8];
  const float* w1     = (const float*)d_in[9];
  const float* b1     = (const float*)d_in[10];
  const float* w2     = (const float*)d_in[11];
  const float* b2     = (const float*)d_in[12];
  const float* w3     = (const float*)d_in[13];
  const float* b3     = (const float*)d_in[14];

  float* ws = (float*)d_ws;
  float* h      = ws;                    // 128*256*169   = 5537792
  float* p      = h + 5537792;           // 128*256*121   = 3964928
  float* caps   = p + 3964928;           // 128*3872*8    = 3964928
  float* mean   = caps + 3964928;        // 256
  float* istd   = mean + 256;            // 256
  float* osum   = istd + 256;            // 32768
  float* spart  = osum + 32768;          // 121*32768     = 3964928
  float* outb   = spart + 3964928;       // 32768
  float* masked = outb + 32768;          // 32768
  float* r1     = masked + 32768;        // 128*328 = 41984
  float* r2     = r1 + 41984;            // 128*192 = 24576
  unsigned short* wpk = (unsigned short*)(r2 + 24576);   // 589824 bf16
  // Wp aliases h+p region (dead after squash_caps): 7933952 floats
  float* Wp     = ws;

  float* length_out = (float*)d_out;           // 2048
  float* recon      = (float*)d_out + 2048;    // 864000

  // conv stem
  {
    int total = NB * OC * H1;
    conv1_k<<<(total + 255) / 256, 256, 0, stream>>>(x, conv1w, conv1b, h);
  }
  bn_stats_k<<<OC, 256, 0, stream>>>(h, mean, istd);
  bn_apply_k<<<NB * OC, 256, 0, stream>>>(h, mean, istd, gamma, beta);

  pack_w2_k<<<589824 / 256, 256, 0, stream>>>(conv2w, wpk);
  conv2_mfma_k<<<256, 512, 0, stream>>>(h, wpk, conv2b, p);

  {
    int total = NB * NCAPS;
    squash_caps_k<<<(total + 255) / 256, 256, 0, stream>>>(p, caps);
  }

  // h & p are dead now -> pack caps_w into their region
  pack_cw_k<<<7933952 / 256, 256, 0, stream>>>(capsw, Wp);

  // dynamic routing (3 iterations), osum = sum of previous outs
  hipMemsetAsync(osum, 0, 32768 * sizeof(float), stream);
  for (int it = 0; it < 3; ++it) {
    route_k<<<968, 256, 0, stream>>>(caps, Wp, osum, spart);
    combine_squash_k<<<128, 256, 0, stream>>>(spart, osum, outb, y, masked,
                                              length_out, it == 2 ? 1 : 0);
  }

  // decoder
  dec1_k<<<(NB * D1 + 255) / 256, 256, 0, stream>>>(masked, w1, b1, r1);
  dec2_k<<<(NB * D2 + 255) / 256, 256, 0, stream>>>(r1, w2, b2, r2);
  dec3_k<<<dim3((OUTPIX + 63) / 64, 2), 256, 0, stream>>>(r2, w3, b3, recon);
}

// Round 5
// 642.381 us; speedup vs baseline: 4.1422x; 1.9435x over previous
//
#include <hip/hip_runtime.h>
#include <hip/hip_bf16.h>

// Sizes
#define NB 128
#define CIN 30
#define HW 15
#define OC 256
#define H1 13   // conv1 out
#define H2 11   // conv2 out
#define NCAPS 3872
#define IND 8
#define OUTD 16
#define CLS 16
#define D1 328
#define D2 192
#define OUTPIX 6750   // 30*15*15
#define NSPLIT 121
#define NPB 32        // 121*32 = 3872 exactly
#define RN 2          // n's per LDS buffer round
#define ROUNDS 16     // NPB/RN

typedef __attribute__((ext_vector_type(8))) short short8_t;
typedef __attribute__((ext_vector_type(4))) float f32x4;

__device__ inline unsigned bf16rne(float f) {
  unsigned u = __builtin_bit_cast(unsigned, f);
  return (u + 0x7FFF + ((u >> 16) & 1)) >> 16;
}

// ---------------- conv1: x[128,30,15,15] -> h[128,256,13,13] ----------------
__global__ __launch_bounds__(256) void conv1_k(const float* __restrict__ x,
    const float* __restrict__ w, const float* __restrict__ bias, float* __restrict__ h) {
  int tid = blockIdx.x * blockDim.x + threadIdx.x;
  const int total = NB * OC * H1;
  if (tid >= total) return;
  int oy = tid % H1;
  int q = tid / H1;          // b*256+oc
  int oc = q & 255;
  int b = q >> 8;
  float acc[H1];
  float bs = bias[oc];
#pragma unroll
  for (int i = 0; i < H1; i++) acc[i] = bs;
  const float* xb = x + b * CIN * HW * HW;
  const float* wb = w + oc * CIN * 9;
  for (int ic = 0; ic < CIN; ic++) {
    const float* xc = xb + ic * (HW * HW) + oy * HW;
    float wv[9];
#pragma unroll
    for (int t = 0; t < 9; t++) wv[t] = wb[ic * 9 + t];
#pragma unroll
    for (int ky = 0; ky < 3; ky++) {
      float xr[HW];
#pragma unroll
      for (int xx = 0; xx < HW; xx++) xr[xx] = xc[ky * HW + xx];
#pragma unroll
      for (int kx = 0; kx < 3; kx++) {
        float wvv = wv[ky * 3 + kx];
#pragma unroll
        for (int ox = 0; ox < H1; ox++) acc[ox] += xr[ox + kx] * wvv;
      }
    }
  }
  float* hp = h + q * (H1 * H1) + oy * H1;
#pragma unroll
  for (int ox = 0; ox < H1; ox++) hp[ox] = acc[ox];
}

// ---------------- BN stats ---------------------------------------------------
__global__ __launch_bounds__(256) void bn_stats_k(const float* __restrict__ h,
    float* __restrict__ mean, float* __restrict__ istd) {
  int c = blockIdx.x;
  int t = threadIdx.x;
  float s = 0.f, s2 = 0.f;
  const int per = H1 * H1;               // 169
  for (int i = t; i < NB * per; i += 256) {
    int b = i / per, pos = i - b * per;
    float v = h[(b * OC + c) * per + pos];
    s += v; s2 += v * v;
  }
  __shared__ float ls[256], ls2[256];
  ls[t] = s; ls2[t] = s2; __syncthreads();
  for (int off = 128; off > 0; off >>= 1) {
    if (t < off) { ls[t] += ls[t + off]; ls2[t] += ls2[t + off]; }
    __syncthreads();
  }
  if (t == 0) {
    const float inv_n = 1.0f / (NB * per);
    float m = ls[0] * inv_n;
    float v = ls2[0] * inv_n - m * m;
    mean[c] = m;
    istd[c] = rsqrtf(v + 1e-5f);
  }
}

// ---------------- BN apply + relu -------------------------------------------
__global__ __launch_bounds__(256) void bn_apply_k(float* __restrict__ h,
    const float* __restrict__ mean, const float* __restrict__ istd,
    const float* __restrict__ gamma, const float* __restrict__ beta) {
  int bc = blockIdx.x;           // b*256+c
  int c = bc & 255;
  int t = threadIdx.x;
  if (t >= H1 * H1) return;
  float v = h[bc * (H1 * H1) + t];
  v = (v - mean[c]) * istd[c] * gamma[c] + beta[c];
  h[bc * (H1 * H1) + t] = fmaxf(v, 0.0f);
}

// ---------------- pack conv2 weights to MFMA layout -------------------------
__global__ __launch_bounds__(256) void pack_w2_k(const float* __restrict__ w,
    unsigned short* __restrict__ wpk) {
  int tid = blockIdx.x * blockDim.x + threadIdx.x;    // 589824
  int e = tid & 7;
  int oc = (tid >> 3) & 255;
  int icchunk = (tid >> 11) & 31;
  int kykx = tid >> 16;
  int ic = icchunk * 8 + e;
  wpk[tid] = (unsigned short)bf16rne(w[((size_t)oc * 256 + ic) * 9 + kykx]);
}

// ---------------- conv2 via bf16 MFMA implicit GEMM -------------------------
__global__ __launch_bounds__(512, 1) void conv2_mfma_k(
    const float* __restrict__ h, const unsigned short* __restrict__ wpk,
    const float* __restrict__ bias, float* __restrict__ p) {
  __shared__ char smem[169 * 544];       // 91936 B; reused for C transpose
  unsigned* hs32 = (unsigned*)smem;      // [pix][136] u32  (272 bf16, 16 pad)
  int bid = blockIdx.x;                  // 0..255
  int b = bid >> 1;
  int nh = bid & 1;                      // oc half
  int t = threadIdx.x;
  int l = t & 63, wid = t >> 6;

  {
    const float* hb = h + (size_t)b * 256 * 169;
    for (int icp = wid; icp < 128; icp += 8) {
      const float* s0 = hb + (size_t)icp * 2 * 169;
#pragma unroll
      for (int pb = 0; pb < 3; pb++) {
        int pix = pb * 64 + l;
        if (pix < 169) {
          unsigned u0 = bf16rne(s0[pix]);
          unsigned u1 = bf16rne(s0[169 + pix]);
          hs32[pix * 136 + icp] = u0 | (u1 << 16);
        }
      }
    }
  }
  __syncthreads();

  int wm = wid & 1;        // m offset wm*64
  int wn = wid >> 1;       // n offset wn*32
  int row = l & 15, kc = l >> 4;
  int ocb = nh * 128 + wn * 32;

  int abase[4];
#pragma unroll
  for (int mf = 0; mf < 4; mf++) {
    int m = wm * 64 + mf * 16 + row;
    int p0 = (m < 121) ? ((m / 11) * 13 + (m % 11)) : 0;
    abase[mf] = p0 * 544 + kc * 16;
  }

  f32x4 acc[4][2];
#pragma unroll
  for (int mf = 0; mf < 4; mf++)
#pragma unroll
    for (int nf = 0; nf < 2; nf++)
      acc[mf][nf] = (f32x4){0.f, 0.f, 0.f, 0.f};

  const size_t lanebase = ((size_t)kc * 256 + ocb + row) * 8;
  const char* lds_base = (const char*)smem;

  for (int ky = 0; ky < 3; ky++) {
    for (int kx = 0; kx < 3; kx++) {
      int r = ky * 3 + kx;
      int koff = (ky * 13 + kx) * 544;
#pragma unroll
      for (int ks = 0; ks < 8; ks++) {
        short8_t bfr[2];
#pragma unroll
        for (int nf = 0; nf < 2; nf++) {
          size_t idx = lanebase + (size_t)(r * 32 + ks * 4) * 2048 + nf * 128;
          bfr[nf] = *(const short8_t*)(wpk + idx);
        }
        short8_t af[4];
#pragma unroll
        for (int mf = 0; mf < 4; mf++)
          af[mf] = *(const short8_t*)(lds_base + (abase[mf] + koff + ks * 64));
#pragma unroll
        for (int mf = 0; mf < 4; mf++)
#pragma unroll
          for (int nf = 0; nf < 2; nf++)
            acc[mf][nf] = __builtin_amdgcn_mfma_f32_16x16x32_bf16(
                af[mf], bfr[nf], acc[mf][nf], 0, 0, 0);
      }
    }
  }

  __syncthreads();
  float* cl = (float*)smem;              // [ocl 0..127][132 m-pad]
#pragma unroll
  for (int nf = 0; nf < 2; nf++) {
    int ocl = wn * 32 + nf * 16 + row;
#pragma unroll
    for (int mf = 0; mf < 4; mf++) {
      int m0 = wm * 64 + mf * 16 + kc * 4;
      f32x4 v = acc[mf][nf];
      *(f32x4*)&cl[ocl * 132 + m0] = v;
    }
  }
  __syncthreads();
  for (int idx = t; idx < 128 * 128; idx += 512) {
    int ocl = idx >> 7, m = idx & 127;
    if (m < 121) {
      int oc = nh * 128 + ocl;
      p[((size_t)b * 256 + oc) * 121 + m] = cl[ocl * 132 + m] + bias[oc];
    }
  }
}

// ---------------- squash primary caps ---------------------------------------
__global__ __launch_bounds__(256) void squash_caps_k(const float* __restrict__ p,
    float* __restrict__ caps) {
  int tid = blockIdx.x * blockDim.x + threadIdx.x;
  const int total = NB * NCAPS;
  if (tid >= total) return;
  const float4* src = (const float4*)(p + (size_t)tid * 8);
  float4 a = src[0], b4 = src[1];
  float n2 = a.x * a.x + a.y * a.y + a.z * a.z + a.w * a.w +
             b4.x * b4.x + b4.y * b4.y + b4.z * b4.z + b4.w * b4.w;
  float nrm = sqrtf(n2);
  float scale = n2 / (1.0f + n2) / (nrm + 1e-8f);
  a.x *= scale; a.y *= scale; a.z *= scale; a.w *= scale;
  b4.x *= scale; b4.y *= scale; b4.z *= scale; b4.w *= scale;
  float4* dst = (float4*)(caps + (size_t)tid * 8);
  dst[0] = a; dst[1] = b4;
}

// ---------------- pack caps_w: cw[o][n][i][j] -> Wp[n][o][i][j] -------------
__global__ __launch_bounds__(256) void pack_cw_k(const float* __restrict__ cw,
    float* __restrict__ Wp) {
  int idx = blockIdx.x * blockDim.x + threadIdx.x;   // 7933952
  int j = idx & 7;
  int i = (idx >> 3) & 15;
  int o = (idx >> 7) & 15;
  int n = idx >> 11;
  Wp[idx] = cw[(((size_t)o * NCAPS + n) * 16 + i) * 8 + j];
}

// ---------------- routing pass v4: fully scalarized (no spillable arrays) ---
// block = one of 968 (split 0..120 x btile 0..7): 256 thr = 16 b x 16 o.
// LDS wl[2 buf][2 n][16 o][132 pad]; one barrier per 2-n round.
// All per-thread state is named f32x4 quads -> SROA guaranteed, no scratch.
#define DOT8(ii) ( [&]{ f32x4 a_ = *(const f32x4*)(wp + (ii) * 8); \
                        f32x4 b_ = *(const f32x4*)(wp + (ii) * 8 + 4); \
                        return a_.x * c0.x + a_.y * c0.y + a_.z * c0.z + a_.w * c0.w + \
                               b_.x * c1.x + b_.y * c1.y + b_.z * c1.z + b_.w * c1.w; }() )

__global__ __launch_bounds__(256) void route_k(const float* __restrict__ caps,
    const float* __restrict__ Wp, const float* __restrict__ osum,
    float* __restrict__ spart) {
  __shared__ float wl[2][RN * 16 * 132];   // 33792 B
  int id = blockIdx.x;                     // 0..967
  int s = (id & 7) * 121 + (id >> 3);      // chunked XCD swizzle
  int split = s >> 3;                      // 0..120
  int btile = s & 7;                       // 0..7
  int t = threadIdx.x;                     // 0..255
  int o = t & 15;
  int bl = t >> 4;                         // 0..15
  int b = btile * 16 + bl;

  const float* op = osum + (b * 16 + o) * 16;
  f32x4 os0 = *(const f32x4*)(op);
  f32x4 os1 = *(const f32x4*)(op + 4);
  f32x4 os2 = *(const f32x4*)(op + 8);
  f32x4 os3 = *(const f32x4*)(op + 12);
  f32x4 sa0 = {0.f,0.f,0.f,0.f}, sa1 = {0.f,0.f,0.f,0.f};
  f32x4 sa2 = {0.f,0.f,0.f,0.f}, sa3 = {0.f,0.f,0.f,0.f};

  int nbeg = split * NPB;
  const float4* src = (const float4*)(Wp + (size_t)nbeg * 2048);

  // staging dest offsets: g = 1024*q + 4*t -> ((g>>11)*16 + ((g>>7)&15))*132 + (g&127)
  int g0 = 4 * t, g1 = 1024 + 4 * t, g2 = 2048 + 4 * t, g3 = 3072 + 4 * t;
  int d0 = ((g0 >> 11) * 16 + ((g0 >> 7) & 15)) * 132 + (g0 & 127);
  int d1 = ((g1 >> 11) * 16 + ((g1 >> 7) & 15)) * 132 + (g1 & 127);
  int d2 = ((g2 >> 11) * 16 + ((g2 >> 7) & 15)) * 132 + (g2 & 127);
  int d3 = ((g3 >> 11) * 16 + ((g3 >> 7) & 15)) * 132 + (g3 & 127);

  // prologue: stage round 0 into buf 0
  {
    float4 v0 = src[t], v1 = src[256 + t], v2 = src[512 + t], v3 = src[768 + t];
    *(float4*)&wl[0][d0] = v0; *(float4*)&wl[0][d1] = v1;
    *(float4*)&wl[0][d2] = v2; *(float4*)&wl[0][d3] = v3;
  }
  __syncthreads();

  for (int r = 0; r < ROUNDS; r++) {
    float4 nv0, nv1, nv2, nv3;
    if (r < ROUNDS - 1) {
      const float4* s2 = src + (r + 1) * 1024;
      nv0 = s2[t]; nv1 = s2[256 + t]; nv2 = s2[512 + t]; nv3 = s2[768 + t];
    }
    const float* wlb = wl[r & 1];
#pragma unroll
    for (int nl = 0; nl < RN; nl++) {
      int n = nbeg + r * RN + nl;
      const float4* cp = (const float4*)(caps + ((size_t)b * NCAPS + n) * 8);
      float4 c0 = cp[0], c1 = cp[1];
      const float* wp = wlb + nl * (16 * 132) + o * 132;
      f32x4 xh0, xh1, xh2, xh3;
      xh0.x = DOT8(0);  xh0.y = DOT8(1);  xh0.z = DOT8(2);  xh0.w = DOT8(3);
      xh1.x = DOT8(4);  xh1.y = DOT8(5);  xh1.z = DOT8(6);  xh1.w = DOT8(7);
      xh2.x = DOT8(8);  xh2.y = DOT8(9);  xh2.z = DOT8(10); xh2.w = DOT8(11);
      xh3.x = DOT8(12); xh3.y = DOT8(13); xh3.z = DOT8(14); xh3.w = DOT8(15);
      float blog =
          os0.x * xh0.x + os0.y * xh0.y + os0.z * xh0.z + os0.w * xh0.w +
          os1.x * xh1.x + os1.y * xh1.y + os1.z * xh1.z + os1.w * xh1.w +
          os2.x * xh2.x + os2.y * xh2.y + os2.z * xh2.z + os2.w * xh2.w +
          os3.x * xh3.x + os3.y * xh3.y + os3.z * xh3.z + os3.w * xh3.w;
      float m = blog;
      m = fmaxf(m, __shfl_xor(m, 1));
      m = fmaxf(m, __shfl_xor(m, 2));
      m = fmaxf(m, __shfl_xor(m, 4));
      m = fmaxf(m, __shfl_xor(m, 8));
      float e = __expf(blog - m);
      float ss = e;
      ss += __shfl_xor(ss, 1);
      ss += __shfl_xor(ss, 2);
      ss += __shfl_xor(ss, 4);
      ss += __shfl_xor(ss, 8);
      float cc = e / ss;
      sa0 += xh0 * cc; sa1 += xh1 * cc; sa2 += xh2 * cc; sa3 += xh3 * cc;
    }
    if (r < ROUNDS - 1) {
      float* dst = wl[(r + 1) & 1];
      *(float4*)&dst[d0] = nv0; *(float4*)&dst[d1] = nv1;
      *(float4*)&dst[d2] = nv2; *(float4*)&dst[d3] = nv3;
      __syncthreads();
    }
  }
  float* sp = spart + (((size_t)split * NB + b) * 16 + o) * 16;
  *(f32x4*)sp = sa0; *(f32x4*)(sp + 4) = sa1;
  *(f32x4*)(sp + 8) = sa2; *(f32x4*)(sp + 12) = sa3;
}

// ---------------- combine partials + squash + osum update -------------------
__global__ __launch_bounds__(256) void combine_squash_k(const float* __restrict__ spart,
    float* __restrict__ osum, float* __restrict__ outbuf, const float* __restrict__ y,
    float* __restrict__ masked, float* __restrict__ length_out, int last) {
  int tid = blockIdx.x * blockDim.x + threadIdx.x;   // 32768 = 128*16*16
  int i = tid & 15;
  int o = (tid >> 4) & 15;
  int b = tid >> 8;
  float s = 0.f;
  for (int k = 0; k < NSPLIT; k++) s += spart[k * 32768 + tid];
  float n2 = s * s;
#pragma unroll
  for (int d = 1; d < 16; d <<= 1) n2 += __shfl_xor(n2, d);
  float nrm = sqrtf(n2);
  float scale = n2 / (1.f + n2) / (nrm + 1e-8f);
  float ov = scale * s;
  outbuf[tid] = ov;
  osum[tid] += ov;
  if (last) {
    masked[tid] = ov * y[b * 16 + o];
    if (i == 0) length_out[b * 16 + o] = scale * nrm;
  }
}

// ---------------- decoder -----------------------------------------------------
__global__ __launch_bounds__(256) void dec1_k(const float* __restrict__ masked,
    const float* __restrict__ w1, const float* __restrict__ b1, float* __restrict__ r1) {
  int tid = blockIdx.x * blockDim.x + threadIdx.x;
  if (tid >= NB * D1) return;
  int j = tid % D1;
  int b = tid / D1;
  const float* mp = masked + b * 256;
  float acc = b1[j];
  for (int k = 0; k < 256; k++) acc += mp[k] * w1[k * D1 + j];
  r1[tid] = 1.f / (1.f + __expf(-acc));
}

__global__ __launch_bounds__(256) void dec2_k(const float* __restrict__ r1,
    const float* __restrict__ w2, const float* __restrict__ b2, float* __restrict__ r2) {
  int tid = blockIdx.x * blockDim.x + threadIdx.x;
  if (tid >= NB * D2) return;
  int j = tid % D2;
  int b = tid / D2;
  const float* rp = r1 + b * D1;
  float acc = b2[j];
  for (int k = 0; k < D1; k++) acc += rp[k] * w2[k * D2 + j];
  r2[tid] = 1.f / (1.f + __expf(-acc));
}

__global__ __launch_bounds__(256) void dec3_k(const float* __restrict__ r2,
    const float* __restrict__ w3, const float* __restrict__ b3, float* __restrict__ recon) {
  __shared__ float r2s[D2 * 64];
  int mt = blockIdx.x, bh = blockIdx.y;
  int t = threadIdx.x;
  int b0 = bh * 64;
  for (int idx = t; idx < D2 * 64; idx += 256) {
    int bb = idx / D2, k = idx - bb * D2;
    r2s[k * 64 + bb] = r2[(b0 + bb) * D2 + k];
  }
  __syncthreads();
  int moff = t & 63, bg = t >> 6;
  int m = mt * 64 + moff;
  if (m >= OUTPIX) return;
  float acc[16];
#pragma unroll
  for (int q = 0; q < 16; q++) acc[q] = 0.f;
  for (int k = 0; k < D2; k++) {
    float wv = w3[k * OUTPIX + m];
    const float4* r4 = (const float4*)&r2s[k * 64 + bg * 16];
#pragma unroll
    for (int v = 0; v < 4; v++) {
      float4 rv = r4[v];
      acc[v * 4 + 0] += wv * rv.x;
      acc[v * 4 + 1] += wv * rv.y;
      acc[v * 4 + 2] += wv * rv.z;
      acc[v * 4 + 3] += wv * rv.w;
    }
  }
  float bias = b3[m];
#pragma unroll
  for (int q = 0; q < 16; q++) {
    int b = b0 + bg * 16 + q;
    recon[(size_t)b * OUTPIX + m] = acc[q] + bias;
  }
}

extern "C" void kernel_launch(void* const* d_in, const int* in_sizes, int n_in,
                              void* d_out, int out_size, void* d_ws, size_t ws_size,
                              hipStream_t stream) {
  const float* x      = (const float*)d_in[0];
  const float* y      = (const float*)d_in[1];
  const float* conv1w = (const float*)d_in[2];
  const float* conv1b = (const float*)d_in[3];
  const float* gamma  = (const float*)d_in[4];
  const float* beta   = (const float*)d_in[5];
  const float* conv2w = (const float*)d_in[6];
  const float* conv2b = (const float*)d_in[7];
  const float* capsw  = (const float*)d_in[8];
  const float* w1     = (const float*)d_in[9];
  const float* b1     = (const float*)d_in[10];
  const float* w2     = (const float*)d_in[11];
  const float* b2     = (const float*)d_in[12];
  const float* w3     = (const float*)d_in[13];
  const float* b3     = (const float*)d_in[14];

  float* ws = (float*)d_ws;
  float* h      = ws;                    // 128*256*169   = 5537792
  float* p      = h + 5537792;           // 128*256*121   = 3964928
  float* caps   = p + 3964928;           // 128*3872*8    = 3964928
  float* mean   = caps + 3964928;        // 256
  float* istd   = mean + 256;            // 256
  float* osum   = istd + 256;            // 32768
  float* spart  = osum + 32768;          // 121*32768     = 3964928
  float* outb   = spart + 3964928;       // 32768
  float* masked = outb + 32768;          // 32768
  float* r1     = masked + 32768;        // 128*328 = 41984
  float* r2     = r1 + 41984;            // 128*192 = 24576
  unsigned short* wpk = (unsigned short*)(r2 + 24576);   // 589824 bf16
  // Wp aliases h+p region (dead after squash_caps): 7933952 floats
  float* Wp     = ws;

  float* length_out = (float*)d_out;           // 2048
  float* recon      = (float*)d_out + 2048;    // 864000

  // conv stem
  {
    int total = NB * OC * H1;
    conv1_k<<<(total + 255) / 256, 256, 0, stream>>>(x, conv1w, conv1b, h);
  }
  bn_stats_k<<<OC, 256, 0, stream>>>(h, mean, istd);
  bn_apply_k<<<NB * OC, 256, 0, stream>>>(h, mean, istd, gamma, beta);

  pack_w2_k<<<589824 / 256, 256, 0, stream>>>(conv2w, wpk);
  conv2_mfma_k<<<256, 512, 0, stream>>>(h, wpk, conv2b, p);

  {
    int total = NB * NCAPS;
    squash_caps_k<<<(total + 255) / 256, 256, 0, stream>>>(p, caps);
  }

  // h & p are dead now -> pack caps_w into their region
  pack_cw_k<<<7933952 / 256, 256, 0, stream>>>(capsw, Wp);

  // dynamic routing (3 iterations), osum = sum of previous outs
  hipMemsetAsync(osum, 0, 32768 * sizeof(float), stream);
  for (int it = 0; it < 3; ++it) {
    route_k<<<968, 256, 0, stream>>>(caps, Wp, osum, spart);
    combine_squash_k<<<128, 256, 0, stream>>>(spart, osum, outb, y, masked,
                                              length_out, it == 2 ? 1 : 0);
  }

  // decoder
  dec1_k<<<(NB * D1 + 255) / 256, 256, 0, stream>>>(masked, w1, b1, r1);
  dec2_k<<<(NB * D2 + 255) / 256, 256, 0, stream>>>(r1, w2, b2, r2);
  dec3_k<<<dim3((OUTPIX + 63) / 64, 2), 256, 0, stream>>>(r2, w3, b3, recon);
}

// Round 6
// 487.245 us; speedup vs baseline: 5.4610x; 1.3184x over previous
//
#include <hip/hip_runtime.h>
#include <hip/hip_bf16.h>

// Sizes
#define NB 128
#define CIN 30
#define HW 15
#define OC 256
#define H1 13   // conv1 out
#define H2 11   // conv2 out
#define NCAPS 3872
#define IND 8
#define OUTD 16
#define CLS 16
#define D1 328
#define D2 192
#define OUTPIX 6750   // 30*15*15
#define NSPLIT 121
#define NPB 32        // 121*32 = 3872 exactly
#define RN 2          // n's per LDS buffer round
#define ROUNDS 16     // NPB/RN

typedef __attribute__((ext_vector_type(8))) short short8_t;
typedef __attribute__((ext_vector_type(4))) float f32x4;

__device__ inline unsigned bf16rne(float f) {
  unsigned u = __builtin_bit_cast(unsigned, f);
  return (u + 0x7FFF + ((u >> 16) & 1)) >> 16;
}

// ---------------- pack conv1 weights: w[oc][ic30][3][3] -> [(tap*4+kc)][oc][8] bf16
__global__ __launch_bounds__(256) void pack_w1_k(const float* __restrict__ w,
    unsigned short* __restrict__ wpk1) {
  int tid = blockIdx.x * blockDim.x + threadIdx.x;   // 73728
  int j = tid & 7;
  int oc = (tid >> 3) & 255;
  int kc = (tid >> 11) & 3;
  int tap = tid >> 13;
  int ic = kc * 8 + j;
  float v = (ic < CIN) ? w[((size_t)oc * CIN + ic) * 9 + tap] : 0.f;
  wpk1[tid] = (unsigned short)bf16rne(v);
}

// ---------------- conv1 via bf16 MFMA implicit GEMM -------------------------
// block = (image, oc-half), 512 thr. A-tile: x image [pix 225][36 bf16] in LDS
// (stride 18 banks -> 16 consecutive pix rows hit 16 distinct banks).
// 8 waves = 8 oc-tiles of 16; each wave: 11 m-frags x 9 taps x K=32 MFMA.
__global__ __launch_bounds__(512, 1) void conv1_mfma_k(
    const float* __restrict__ x, const unsigned short* __restrict__ wpk1,
    const float* __restrict__ bias, float* __restrict__ h) {
  __shared__ char smem[128 * 176 * 4];   // 90112 B; staging uses first 16200 B
  unsigned* hs32 = (unsigned*)smem;      // [pix][18 u32] (36 bf16, 32 data+4 pad)
  int bid = blockIdx.x;                  // 0..255
  int b = bid >> 1;
  int nh = bid & 1;
  int t = threadIdx.x;
  int l = t & 63;
  int wid = t >> 6;

  // stage image: thread t = pixel (225 < 512), 15 real ic-pairs + 1 zero pair
  if (t < 225) {
    const float* xb = x + (size_t)b * (CIN * 225);
#pragma unroll
    for (int icp = 0; icp < 15; icp++) {
      unsigned u0 = bf16rne(xb[(2 * icp) * 225 + t]);
      unsigned u1 = bf16rne(xb[(2 * icp + 1) * 225 + t]);
      hs32[t * 18 + icp] = u0 | (u1 << 16);
    }
    hs32[t * 18 + 15] = 0;               // ic 30,31 zero pad
  }
  __syncthreads();

  int row = l & 15, kc = l >> 4;
  int ocb = nh * 128 + wid * 16;

  int arow[11];
#pragma unroll
  for (int mf = 0; mf < 11; mf++) {
    int m = mf * 16 + row;
    int pix = 0;
    if (m < 169) { int oy = m / 13, ox = m - oy * 13; pix = oy * HW + ox; }
    arow[mf] = pix * 72 + kc * 16;
  }

  f32x4 acc[11];
#pragma unroll
  for (int mf = 0; mf < 11; mf++) acc[mf] = (f32x4){0.f, 0.f, 0.f, 0.f};

  const size_t lanebase = ((size_t)ocb + row) * 8;
  const char* lds_base = (const char*)smem;

#pragma unroll
  for (int tap = 0; tap < 9; tap++) {
    const int ky = tap / 3, kx = tap % 3;
    const int koff = (ky * HW + kx) * 72;
    short8_t bfr = *(const short8_t*)(wpk1 + (size_t)(tap * 4 + kc) * 2048 + lanebase);
#pragma unroll
    for (int mf = 0; mf < 11; mf++) {
      short8_t af = *(const short8_t*)(lds_base + arow[mf] + koff);
      acc[mf] = __builtin_amdgcn_mfma_f32_16x16x32_bf16(af, bfr, acc[mf], 0, 0, 0);
    }
  }

  // transpose C through LDS, store coalesced with bias
  __syncthreads();
  float* cl = (float*)smem;              // [ocl 128][176 m-pad]
  {
    int ocl = wid * 16 + row;            // C col = lane&15 -> oc
#pragma unroll
    for (int mf = 0; mf < 11; mf++) {
      int m0 = mf * 16 + kc * 4;         // C row = (lane>>4)*4 + reg -> pix
      *(f32x4*)&cl[ocl * 176 + m0] = acc[mf];
    }
  }
  __syncthreads();
  for (int idx = t; idx < 128 * 169; idx += 512) {
    int ocl = idx / 169;
    int m = idx - ocl * 169;
    int oc = nh * 128 + ocl;
    h[((size_t)b * 256 + oc) * 169 + m] = cl[ocl * 176 + m] + bias[oc];
  }
}

// ---------------- BN stats ---------------------------------------------------
__global__ __launch_bounds__(256) void bn_stats_k(const float* __restrict__ h,
    float* __restrict__ mean, float* __restrict__ istd) {
  int c = blockIdx.x;
  int t = threadIdx.x;
  float s = 0.f, s2 = 0.f;
  const int per = H1 * H1;               // 169
  for (int i = t; i < NB * per; i += 256) {
    int b = i / per, pos = i - b * per;
    float v = h[(b * OC + c) * per + pos];
    s += v; s2 += v * v;
  }
  __shared__ float ls[256], ls2[256];
  ls[t] = s; ls2[t] = s2; __syncthreads();
  for (int off = 128; off > 0; off >>= 1) {
    if (t < off) { ls[t] += ls[t + off]; ls2[t] += ls2[t + off]; }
    __syncthreads();
  }
  if (t == 0) {
    const float inv_n = 1.0f / (NB * per);
    float m = ls[0] * inv_n;
    float v = ls2[0] * inv_n - m * m;
    mean[c] = m;
    istd[c] = rsqrtf(v + 1e-5f);
  }
}

// ---------------- BN apply + relu -------------------------------------------
__global__ __launch_bounds__(256) void bn_apply_k(float* __restrict__ h,
    const float* __restrict__ mean, const float* __restrict__ istd,
    const float* __restrict__ gamma, const float* __restrict__ beta) {
  int bc = blockIdx.x;           // b*256+c
  int c = bc & 255;
  int t = threadIdx.x;
  if (t >= H1 * H1) return;
  float v = h[bc * (H1 * H1) + t];
  v = (v - mean[c]) * istd[c] * gamma[c] + beta[c];
  h[bc * (H1 * H1) + t] = fmaxf(v, 0.0f);
}

// ---------------- pack conv2 weights to MFMA layout -------------------------
__global__ __launch_bounds__(256) void pack_w2_k(const float* __restrict__ w,
    unsigned short* __restrict__ wpk) {
  int tid = blockIdx.x * blockDim.x + threadIdx.x;    // 589824
  int e = tid & 7;
  int oc = (tid >> 3) & 255;
  int icchunk = (tid >> 11) & 31;
  int kykx = tid >> 16;
  int ic = icchunk * 8 + e;
  wpk[tid] = (unsigned short)bf16rne(w[((size_t)oc * 256 + ic) * 9 + kykx]);
}

// ---------------- conv2 via bf16 MFMA implicit GEMM -------------------------
__global__ __launch_bounds__(512, 1) void conv2_mfma_k(
    const float* __restrict__ h, const unsigned short* __restrict__ wpk,
    const float* __restrict__ bias, float* __restrict__ p) {
  __shared__ char smem[169 * 544];       // 91936 B; reused for C transpose
  unsigned* hs32 = (unsigned*)smem;      // [pix][136] u32  (272 bf16, 16 pad)
  int bid = blockIdx.x;                  // 0..255
  int b = bid >> 1;
  int nh = bid & 1;                      // oc half
  int t = threadIdx.x;
  int l = t & 63, wid = t >> 6;

  {
    const float* hb = h + (size_t)b * 256 * 169;
    for (int icp = wid; icp < 128; icp += 8) {
      const float* s0 = hb + (size_t)icp * 2 * 169;
#pragma unroll
      for (int pb = 0; pb < 3; pb++) {
        int pix = pb * 64 + l;
        if (pix < 169) {
          unsigned u0 = bf16rne(s0[pix]);
          unsigned u1 = bf16rne(s0[169 + pix]);
          hs32[pix * 136 + icp] = u0 | (u1 << 16);
        }
      }
    }
  }
  __syncthreads();

  int wm = wid & 1;        // m offset wm*64
  int wn = wid >> 1;       // n offset wn*32
  int row = l & 15, kc = l >> 4;
  int ocb = nh * 128 + wn * 32;

  int abase[4];
#pragma unroll
  for (int mf = 0; mf < 4; mf++) {
    int m = wm * 64 + mf * 16 + row;
    int p0 = (m < 121) ? ((m / 11) * 13 + (m % 11)) : 0;
    abase[mf] = p0 * 544 + kc * 16;
  }

  f32x4 acc[4][2];
#pragma unroll
  for (int mf = 0; mf < 4; mf++)
#pragma unroll
    for (int nf = 0; nf < 2; nf++)
      acc[mf][nf] = (f32x4){0.f, 0.f, 0.f, 0.f};

  const size_t lanebase = ((size_t)kc * 256 + ocb + row) * 8;
  const char* lds_base = (const char*)smem;

  for (int ky = 0; ky < 3; ky++) {
    for (int kx = 0; kx < 3; kx++) {
      int r = ky * 3 + kx;
      int koff = (ky * 13 + kx) * 544;
#pragma unroll
      for (int ks = 0; ks < 8; ks++) {
        short8_t bfr[2];
#pragma unroll
        for (int nf = 0; nf < 2; nf++) {
          size_t idx = lanebase + (size_t)(r * 32 + ks * 4) * 2048 + nf * 128;
          bfr[nf] = *(const short8_t*)(wpk + idx);
        }
        short8_t af[4];
#pragma unroll
        for (int mf = 0; mf < 4; mf++)
          af[mf] = *(const short8_t*)(lds_base + (abase[mf] + koff + ks * 64));
#pragma unroll
        for (int mf = 0; mf < 4; mf++)
#pragma unroll
          for (int nf = 0; nf < 2; nf++)
            acc[mf][nf] = __builtin_amdgcn_mfma_f32_16x16x32_bf16(
                af[mf], bfr[nf], acc[mf][nf], 0, 0, 0);
      }
    }
  }

  __syncthreads();
  float* cl = (float*)smem;              // [ocl 0..127][132 m-pad]
#pragma unroll
  for (int nf = 0; nf < 2; nf++) {
    int ocl = wn * 32 + nf * 16 + row;
#pragma unroll
    for (int mf = 0; mf < 4; mf++) {
      int m0 = wm * 64 + mf * 16 + kc * 4;
      f32x4 v = acc[mf][nf];
      *(f32x4*)&cl[ocl * 132 + m0] = v;
    }
  }
  __syncthreads();
  for (int idx = t; idx < 128 * 128; idx += 512) {
    int ocl = idx >> 7, m = idx & 127;
    if (m < 121) {
      int oc = nh * 128 + ocl;
      p[((size_t)b * 256 + oc) * 121 + m] = cl[ocl * 132 + m] + bias[oc];
    }
  }
}

// ---------------- squash primary caps ---------------------------------------
__global__ __launch_bounds__(256) void squash_caps_k(const float* __restrict__ p,
    float* __restrict__ caps) {
  int tid = blockIdx.x * blockDim.x + threadIdx.x;
  const int total = NB * NCAPS;
  if (tid >= total) return;
  const float4* src = (const float4*)(p + (size_t)tid * 8);
  float4 a = src[0], b4 = src[1];
  float n2 = a.x * a.x + a.y * a.y + a.z * a.z + a.w * a.w +
             b4.x * b4.x + b4.y * b4.y + b4.z * b4.z + b4.w * b4.w;
  float nrm = sqrtf(n2);
  float scale = n2 / (1.0f + n2) / (nrm + 1e-8f);
  a.x *= scale; a.y *= scale; a.z *= scale; a.w *= scale;
  b4.x *= scale; b4.y *= scale; b4.z *= scale; b4.w *= scale;
  float4* dst = (float4*)(caps + (size_t)tid * 8);
  dst[0] = a; dst[1] = b4;
}

// ---------------- pack caps_w: cw[o][n][i][j] -> Wp[n][o][i][j] -------------
__global__ __launch_bounds__(256) void pack_cw_k(const float* __restrict__ cw,
    float* __restrict__ Wp) {
  int idx = blockIdx.x * blockDim.x + threadIdx.x;   // 7933952
  int j = idx & 7;
  int i = (idx >> 3) & 15;
  int o = (idx >> 7) & 15;
  int n = idx >> 11;
  Wp[idx] = cw[(((size_t)o * NCAPS + n) * 16 + i) * 8 + j];
}

// ---------------- routing pass v4: fully scalarized (no spillable arrays) ---
#define DOT8(ii) ( [&]{ f32x4 a_ = *(const f32x4*)(wp + (ii) * 8); \
                        f32x4 b_ = *(const f32x4*)(wp + (ii) * 8 + 4); \
                        return a_.x * c0.x + a_.y * c0.y + a_.z * c0.z + a_.w * c0.w + \
                               b_.x * c1.x + b_.y * c1.y + b_.z * c1.z + b_.w * c1.w; }() )

__global__ __launch_bounds__(256) void route_k(const float* __restrict__ caps,
    const float* __restrict__ Wp, const float* __restrict__ osum,
    float* __restrict__ spart) {
  __shared__ float wl[2][RN * 16 * 132];   // 33792 B
  int id = blockIdx.x;                     // 0..967
  int s = (id & 7) * 121 + (id >> 3);      // chunked XCD swizzle
  int split = s >> 3;                      // 0..120
  int btile = s & 7;                       // 0..7
  int t = threadIdx.x;                     // 0..255
  int o = t & 15;
  int bl = t >> 4;                         // 0..15
  int b = btile * 16 + bl;

  const float* op = osum + (b * 16 + o) * 16;
  f32x4 os0 = *(const f32x4*)(op);
  f32x4 os1 = *(const f32x4*)(op + 4);
  f32x4 os2 = *(const f32x4*)(op + 8);
  f32x4 os3 = *(const f32x4*)(op + 12);
  f32x4 sa0 = {0.f,0.f,0.f,0.f}, sa1 = {0.f,0.f,0.f,0.f};
  f32x4 sa2 = {0.f,0.f,0.f,0.f}, sa3 = {0.f,0.f,0.f,0.f};

  int nbeg = split * NPB;
  const float4* src = (const float4*)(Wp + (size_t)nbeg * 2048);

  int g0 = 4 * t, g1 = 1024 + 4 * t, g2 = 2048 + 4 * t, g3 = 3072 + 4 * t;
  int d0 = ((g0 >> 11) * 16 + ((g0 >> 7) & 15)) * 132 + (g0 & 127);
  int d1 = ((g1 >> 11) * 16 + ((g1 >> 7) & 15)) * 132 + (g1 & 127);
  int d2 = ((g2 >> 11) * 16 + ((g2 >> 7) & 15)) * 132 + (g2 & 127);
  int d3 = ((g3 >> 11) * 16 + ((g3 >> 7) & 15)) * 132 + (g3 & 127);

  {
    float4 v0 = src[t], v1 = src[256 + t], v2 = src[512 + t], v3 = src[768 + t];
    *(float4*)&wl[0][d0] = v0; *(float4*)&wl[0][d1] = v1;
    *(float4*)&wl[0][d2] = v2; *(float4*)&wl[0][d3] = v3;
  }
  __syncthreads();

  for (int r = 0; r < ROUNDS; r++) {
    float4 nv0, nv1, nv2, nv3;
    if (r < ROUNDS - 1) {
      const float4* s2 = src + (r + 1) * 1024;
      nv0 = s2[t]; nv1 = s2[256 + t]; nv2 = s2[512 + t]; nv3 = s2[768 + t];
    }
    const float* wlb = wl[r & 1];
#pragma unroll
    for (int nl = 0; nl < RN; nl++) {
      int n = nbeg + r * RN + nl;
      const float4* cp = (const float4*)(caps + ((size_t)b * NCAPS + n) * 8);
      float4 c0 = cp[0], c1 = cp[1];
      const float* wp = wlb + nl * (16 * 132) + o * 132;
      f32x4 xh0, xh1, xh2, xh3;
      xh0.x = DOT8(0);  xh0.y = DOT8(1);  xh0.z = DOT8(2);  xh0.w = DOT8(3);
      xh1.x = DOT8(4);  xh1.y = DOT8(5);  xh1.z = DOT8(6);  xh1.w = DOT8(7);
      xh2.x = DOT8(8);  xh2.y = DOT8(9);  xh2.z = DOT8(10); xh2.w = DOT8(11);
      xh3.x = DOT8(12); xh3.y = DOT8(13); xh3.z = DOT8(14); xh3.w = DOT8(15);
      float blog =
          os0.x * xh0.x + os0.y * xh0.y + os0.z * xh0.z + os0.w * xh0.w +
          os1.x * xh1.x + os1.y * xh1.y + os1.z * xh1.z + os1.w * xh1.w +
          os2.x * xh2.x + os2.y * xh2.y + os2.z * xh2.z + os2.w * xh2.w +
          os3.x * xh3.x + os3.y * xh3.y + os3.z * xh3.z + os3.w * xh3.w;
      float m = blog;
      m = fmaxf(m, __shfl_xor(m, 1));
      m = fmaxf(m, __shfl_xor(m, 2));
      m = fmaxf(m, __shfl_xor(m, 4));
      m = fmaxf(m, __shfl_xor(m, 8));
      float e = __expf(blog - m);
      float ss = e;
      ss += __shfl_xor(ss, 1);
      ss += __shfl_xor(ss, 2);
      ss += __shfl_xor(ss, 4);
      ss += __shfl_xor(ss, 8);
      float cc = e / ss;
      sa0 += xh0 * cc; sa1 += xh1 * cc; sa2 += xh2 * cc; sa3 += xh3 * cc;
    }
    if (r < ROUNDS - 1) {
      float* dst = wl[(r + 1) & 1];
      *(float4*)&dst[d0] = nv0; *(float4*)&dst[d1] = nv1;
      *(float4*)&dst[d2] = nv2; *(float4*)&dst[d3] = nv3;
      __syncthreads();
    }
  }
  float* sp = spart + (((size_t)split * NB + b) * 16 + o) * 16;
  *(f32x4*)sp = sa0; *(f32x4*)(sp + 4) = sa1;
  *(f32x4*)(sp + 8) = sa2; *(f32x4*)(sp + 12) = sa3;
}

// ---------------- combine partials + squash + osum update -------------------
__global__ __launch_bounds__(256) void combine_squash_k(const float* __restrict__ spart,
    float* __restrict__ osum, float* __restrict__ outbuf, const float* __restrict__ y,
    float* __restrict__ masked, float* __restrict__ length_out, int last) {
  int tid = blockIdx.x * blockDim.x + threadIdx.x;   // 32768 = 128*16*16
  int i = tid & 15;
  int o = (tid >> 4) & 15;
  int b = tid >> 8;
  float s = 0.f;
  for (int k = 0; k < NSPLIT; k++) s += spart[k * 32768 + tid];
  float n2 = s * s;
#pragma unroll
  for (int d = 1; d < 16; d <<= 1) n2 += __shfl_xor(n2, d);
  float nrm = sqrtf(n2);
  float scale = n2 / (1.f + n2) / (nrm + 1e-8f);
  float ov = scale * s;
  outbuf[tid] = ov;
  osum[tid] += ov;
  if (last) {
    masked[tid] = ov * y[b * 16 + o];
    if (i == 0) length_out[b * 16 + o] = scale * nrm;
  }
}

// ---------------- decoder -----------------------------------------------------
__global__ __launch_bounds__(256) void dec1_k(const float* __restrict__ masked,
    const float* __restrict__ w1, const float* __restrict__ b1, float* __restrict__ r1) {
  int tid = blockIdx.x * blockDim.x + threadIdx.x;
  if (tid >= NB * D1) return;
  int j = tid % D1;
  int b = tid / D1;
  const float* mp = masked + b * 256;
  float acc = b1[j];
  for (int k = 0; k < 256; k++) acc += mp[k] * w1[k * D1 + j];
  r1[tid] = 1.f / (1.f + __expf(-acc));
}

__global__ __launch_bounds__(256) void dec2_k(const float* __restrict__ r1,
    const float* __restrict__ w2, const float* __restrict__ b2, float* __restrict__ r2) {
  int tid = blockIdx.x * blockDim.x + threadIdx.x;
  if (tid >= NB * D2) return;
  int j = tid % D2;
  int b = tid / D2;
  const float* rp = r1 + b * D1;
  float acc = b2[j];
  for (int k = 0; k < D1; k++) acc += rp[k] * w2[k * D2 + j];
  r2[tid] = 1.f / (1.f + __expf(-acc));
}

__global__ __launch_bounds__(256) void dec3_k(const float* __restrict__ r2,
    const float* __restrict__ w3, const float* __restrict__ b3, float* __restrict__ recon) {
  __shared__ float r2s[D2 * 64];
  int mt = blockIdx.x, bh = blockIdx.y;
  int t = threadIdx.x;
  int b0 = bh * 64;
  for (int idx = t; idx < D2 * 64; idx += 256) {
    int bb = idx / D2, k = idx - bb * D2;
    r2s[k * 64 + bb] = r2[(b0 + bb) * D2 + k];
  }
  __syncthreads();
  int moff = t & 63, bg = t >> 6;
  int m = mt * 64 + moff;
  if (m >= OUTPIX) return;
  float acc[16];
#pragma unroll
  for (int q = 0; q < 16; q++) acc[q] = 0.f;
  for (int k = 0; k < D2; k++) {
    float wv = w3[k * OUTPIX + m];
    const float4* r4 = (const float4*)&r2s[k * 64 + bg * 16];
#pragma unroll
    for (int v = 0; v < 4; v++) {
      float4 rv = r4[v];
      acc[v * 4 + 0] += wv * rv.x;
      acc[v * 4 + 1] += wv * rv.y;
      acc[v * 4 + 2] += wv * rv.z;
      acc[v * 4 + 3] += wv * rv.w;
    }
  }
  float bias = b3[m];
#pragma unroll
  for (int q = 0; q < 16; q++) {
    int b = b0 + bg * 16 + q;
    recon[(size_t)b * OUTPIX + m] = acc[q] + bias;
  }
}

extern "C" void kernel_launch(void* const* d_in, const int* in_sizes, int n_in,
                              void* d_out, int out_size, void* d_ws, size_t ws_size,
                              hipStream_t stream) {
  const float* x      = (const float*)d_in[0];
  const float* y      = (const float*)d_in[1];
  const float* conv1w = (const float*)d_in[2];
  const float* conv1b = (const float*)d_in[3];
  const float* gamma  = (const float*)d_in[4];
  const float* beta   = (const float*)d_in[5];
  const float* conv2w = (const float*)d_in[6];
  const float* conv2b = (const float*)d_in[7];
  const float* capsw  = (const float*)d_in[8];
  const float* w1     = (const float*)d_in[9];
  const float* b1     = (const float*)d_in[10];
  const float* w2     = (const float*)d_in[11];
  const float* b2     = (const float*)d_in[12];
  const float* w3     = (const float*)d_in[13];
  const float* b3     = (const float*)d_in[14];

  float* ws = (float*)d_ws;
  float* h      = ws;                    // 128*256*169   = 5537792
  float* p      = h + 5537792;           // 128*256*121   = 3964928
  float* caps   = p + 3964928;           // 128*3872*8    = 3964928
  float* mean   = caps + 3964928;        // 256
  float* istd   = mean + 256;            // 256
  float* osum   = istd + 256;            // 32768
  float* spart  = osum + 32768;          // 121*32768     = 3964928
  float* outb   = spart + 3964928;       // 32768
  float* masked = outb + 32768;          // 32768
  float* r1     = masked + 32768;        // 128*328 = 41984
  float* r2     = r1 + 41984;            // 128*192 = 24576
  unsigned short* wpk = (unsigned short*)(r2 + 24576);   // 589824 bf16
  unsigned short* wpk1 = wpk + 589824;   // 73728 bf16
  // Wp aliases h+p region (dead after squash_caps): 7933952 floats
  float* Wp     = ws;

  float* length_out = (float*)d_out;           // 2048
  float* recon      = (float*)d_out + 2048;    // 864000

  // conv stem (both convs via MFMA)
  pack_w1_k<<<73728 / 256, 256, 0, stream>>>(conv1w, wpk1);
  conv1_mfma_k<<<256, 512, 0, stream>>>(x, wpk1, conv1b, h);
  bn_stats_k<<<OC, 256, 0, stream>>>(h, mean, istd);
  bn_apply_k<<<NB * OC, 256, 0, stream>>>(h, mean, istd, gamma, beta);

  pack_w2_k<<<589824 / 256, 256, 0, stream>>>(conv2w, wpk);
  conv2_mfma_k<<<256, 512, 0, stream>>>(h, wpk, conv2b, p);

  {
    int total = NB * NCAPS;
    squash_caps_k<<<(total + 255) / 256, 256, 0, stream>>>(p, caps);
  }

  // h & p are dead now -> pack caps_w into their region
  pack_cw_k<<<7933952 / 256, 256, 0, stream>>>(capsw, Wp);

  // dynamic routing (3 iterations), osum = sum of previous outs
  hipMemsetAsync(osum, 0, 32768 * sizeof(float), stream);
  for (int it = 0; it < 3; ++it) {
    route_k<<<968, 256, 0, stream>>>(caps, Wp, osum, spart);
    combine_squash_k<<<128, 256, 0, stream>>>(spart, osum, outb, y, masked,
                                              length_out, it == 2 ? 1 : 0);
  }

  // decoder
  dec1_k<<<(NB * D1 + 255) / 256, 256, 0, stream>>>(masked, w1, b1, r1);
  dec2_k<<<(NB * D2 + 255) / 256, 256, 0, stream>>>(r1, w2, b2, r2);
  dec3_k<<<dim3((OUTPIX + 63) / 64, 2), 256, 0, stream>>>(r2, w3, b3, recon);
}